// Round 2
// baseline (205.959 us; speedup 1.0000x reference)
//
#include <hip/hip_runtime.h>
#include <hip/hip_fp16.h>

#define N_NODES 50000
#define N_EDGES 800000
#define N_FEAT 128
#define HIDDEN 64
#define N_CLASSES 16
#define NBLK_NODE 196   // number of 256-node dst tiles (ceil(50000/256))
#define TCAP 8192       // per-tile bucket capacity (recs); mean 4083, sigma ~64

typedef _Float16 f16x8 __attribute__((ext_vector_type(8)));
typedef float f32x4 __attribute__((ext_vector_type(4)));

// tileCur[t] = t*TCAP (bucket base cursors)
__global__ void k_init(int* __restrict__ tileCur) {
    int tid = threadIdx.x;
    if (tid < NBLK_NODE) tileCur[tid] = tid * TCAP;
}

// Partition edges into 196 fixed-capacity dst-tile buckets. Per block: LDS
// histogram, ONE global atomic per (block,tile) reserves a contiguous sub-run
// -> block-owned 4B record stores merge in L2. record: src | dstLocal<<16
__global__ __launch_bounds__(256) void k_part(const int* __restrict__ ei,
                                              int* __restrict__ tileCur,
                                              int* __restrict__ binned) {
    __shared__ int cnt[NBLK_NODE], base[NBLK_NODE], cur[NBLK_NODE];
    int tid = threadIdx.x;
    int start = blockIdx.x * 4096;
    if (tid < NBLK_NODE) cnt[tid] = 0;
    __syncthreads();
    int s[16], d[16];
#pragma unroll
    for (int u = 0; u < 4; ++u) {
        int e0 = start + u * 1024 + tid * 4;
        if (e0 + 4 <= N_EDGES) {
            int4 s4 = *(const int4*)&ei[e0];
            int4 d4 = *(const int4*)&ei[N_EDGES + e0];
            s[u * 4 + 0] = s4.x; s[u * 4 + 1] = s4.y; s[u * 4 + 2] = s4.z; s[u * 4 + 3] = s4.w;
            d[u * 4 + 0] = d4.x; d[u * 4 + 1] = d4.y; d[u * 4 + 2] = d4.z; d[u * 4 + 3] = d4.w;
#pragma unroll
            for (int q = 0; q < 4; ++q) atomicAdd(&cnt[d[u * 4 + q] >> 8], 1);
        } else {
#pragma unroll
            for (int q = 0; q < 4; ++q) {
                int e = e0 + q;
                if (e < N_EDGES) {
                    s[u * 4 + q] = ei[e];
                    d[u * 4 + q] = ei[N_EDGES + e];
                    atomicAdd(&cnt[d[u * 4 + q] >> 8], 1);
                } else s[u * 4 + q] = -1;
            }
        }
    }
    __syncthreads();
    if (tid < NBLK_NODE) {
        base[tid] = atomicAdd(&tileCur[tid], cnt[tid]);
        cur[tid] = 0;
    }
    __syncthreads();
#pragma unroll
    for (int u = 0; u < 16; ++u) {
        if (s[u] < 0) continue;
        int t = d[u] >> 8;
        int r = atomicAdd(&cur[t], 1);
        int p = base[t] + r;
        if (p < (t + 1) * TCAP)  // bucket-bound guard (never hit for uniform input)
            binned[p] = s[u] | ((d[u] & 255) << 16);
    }
}

// Per-tile counting sort (bucketed layout) — round-0 verbatim (measured-good).
// Also derives degree -> dinv and per-node {start,count} rse.
__global__ __launch_bounds__(256) void k_finesort(const int* __restrict__ binned,
                                                  const int* __restrict__ tileCur,
                                                  int* __restrict__ csr,
                                                  int2* __restrict__ rse,
                                                  float* __restrict__ dinv) {
    __shared__ int stage[TCAP];
    __shared__ int sc[256];
    __shared__ int cnt256[256];
    __shared__ int nodeOff[256];
    int tid = threadIdx.x;
    int tb = blockIdx.x;
    int beg = tb * TCAP;
    int m = tileCur[tb] - beg;
    if (m > TCAP) m = TCAP;
    cnt256[tid] = 0;
    __syncthreads();
    const int4* b4 = (const int4*)(binned + beg);
    int nv = m >> 2;
    for (int i = tid; i < nv; i += 256) {
        int4 r = b4[i];
        atomicAdd(&cnt256[(r.x >> 16) & 255], 1);
        atomicAdd(&cnt256[(r.y >> 16) & 255], 1);
        atomicAdd(&cnt256[(r.z >> 16) & 255], 1);
        atomicAdd(&cnt256[(r.w >> 16) & 255], 1);
    }
    for (int i = (m & ~3) + tid; i < m; i += 256)
        atomicAdd(&cnt256[(binned[beg + i] >> 16) & 255], 1);
    __syncthreads();
    int myc = cnt256[tid];
    sc[tid] = myc;
    __syncthreads();
#pragma unroll
    for (int off = 1; off < 256; off <<= 1) {
        int t = (tid >= off) ? sc[tid - off] : 0;
        __syncthreads();
        sc[tid] += t;
        __syncthreads();
    }
    int off0 = sc[tid] - myc;
    nodeOff[tid] = off0;
    int gnode = tb * 256 + tid;
    if (gnode < N_NODES) {
        dinv[gnode] = rsqrtf((float)myc + 1.0f);  // deg = in-edges + self-loop
        rse[gnode] = make_int2(beg + off0, myc);
    }
    cnt256[tid] = 0;
    __syncthreads();
    for (int i = tid; i < nv; i += 256) {
        int4 r = b4[i];
        int rr;
        rr = atomicAdd(&cnt256[(r.x >> 16) & 255], 1); stage[nodeOff[(r.x >> 16) & 255] + rr] = r.x & 0xFFFF;
        rr = atomicAdd(&cnt256[(r.y >> 16) & 255], 1); stage[nodeOff[(r.y >> 16) & 255] + rr] = r.y & 0xFFFF;
        rr = atomicAdd(&cnt256[(r.z >> 16) & 255], 1); stage[nodeOff[(r.z >> 16) & 255] + rr] = r.z & 0xFFFF;
        rr = atomicAdd(&cnt256[(r.w >> 16) & 255], 1); stage[nodeOff[(r.w >> 16) & 255] + rr] = r.w & 0xFFFF;
    }
    for (int i = (m & ~3) + tid; i < m; i += 256) {
        int rec = binned[beg + i];
        int dl = (rec >> 16) & 255;
        int rr = atomicAdd(&cnt256[dl], 1);
        stage[nodeOff[dl] + rr] = rec & 0xFFFF;
    }
    __syncthreads();
    int4* c4 = (int4*)(csr + beg);
    for (int i = tid; i < nv; i += 256) c4[i] = ((const int4*)stage)[i];
    for (int i = (m & ~3) + tid; i < m; i += 256) csr[beg + i] = stage[i];
}

// ---- MFMA GEMM: out[n,f] = (A @ W)[n,f] * dinv[n], fp16 out ----
// Block = 256 thr = 4 waves = 64 nodes; wave w covers nodes nbase+16w..+15.
// mfma_f32_16x16x32_f16; A-frag A[m=lane&15][k=quad*8+j]; B-frag
// B[k=quad*8+j][n=lane&15]; D row=quad*4+reg, col=lane&15 (verified layouts).
// A and W staged k-contiguous in LDS, stride K+8 halves (2-way banks = free).
template <int K, typename TIn>
__global__ __launch_bounds__(256) void k_mm(const TIn* __restrict__ a,
                                            const float* __restrict__ w,
                                            const float* __restrict__ dinv,
                                            __half* __restrict__ out) {
    constexpr int LDK = K + 8;
    __shared__ __align__(16) __half A_lds[64 * LDK];
    __shared__ __align__(16) __half Wt_lds[64 * LDK];
    int tid = threadIdx.x;
    long nbase = (long)blockIdx.x * 64;

    // stage W transposed: w[k*64+f] (fp32) -> Wt_lds[f][k] (fp16)
    for (int i = tid; i < K * 16; i += 256) {
        int k = (i * 4) >> 6;
        int f0 = (i * 4) & 63;
        float4 v = *(const float4*)&w[i * 4];
        Wt_lds[(f0 + 0) * LDK + k] = __float2half(v.x);
        Wt_lds[(f0 + 1) * LDK + k] = __float2half(v.y);
        Wt_lds[(f0 + 2) * LDK + k] = __float2half(v.z);
        Wt_lds[(f0 + 3) * LDK + k] = __float2half(v.w);
    }
    // stage A rows -> A_lds[n][k] fp16 (8-elem chunks)
    for (int i = tid; i < 64 * K / 8; i += 256) {
        int n = (i * 8) / K;
        int k0 = (i * 8) % K;
        long gn = nbase + n;
        if constexpr (sizeof(TIn) == 4) {
            float4 v0, v1;
            if (gn < N_NODES) {
                v0 = *(const float4*)&a[gn * K + k0];
                v1 = *(const float4*)&a[gn * K + k0 + 4];
            } else {
                v0 = make_float4(0.f, 0.f, 0.f, 0.f);
                v1 = v0;
            }
            __half2* dst = (__half2*)&A_lds[n * LDK + k0];
            dst[0] = __floats2half2_rn(v0.x, v0.y);
            dst[1] = __floats2half2_rn(v0.z, v0.w);
            dst[2] = __floats2half2_rn(v1.x, v1.y);
            dst[3] = __floats2half2_rn(v1.z, v1.w);
        } else {
            int4 v = (gn < N_NODES) ? *(const int4*)&a[gn * K + k0]
                                    : make_int4(0, 0, 0, 0);
            *(int4*)&A_lds[n * LDK + k0] = v;
        }
    }
    __syncthreads();

    int wv = tid >> 6;
    int lane = tid & 63;
    int m = lane & 15;      // A row within wave tile / D col
    int quad = lane >> 4;   // 0..3
    const __half* Arow = &A_lds[(wv * 16 + m) * LDK + quad * 8];
    f32x4 acc[4] = {};      // 4 feature col-tiles of 16
#pragma unroll
    for (int t = 0; t < K; t += 32) {
        f16x8 af = *(const f16x8*)(const void*)&Arow[t];
#pragma unroll
        for (int g = 0; g < 4; ++g) {
            f16x8 bf = *(const f16x8*)(const void*)&Wt_lds[(g * 16 + m) * LDK + t + quad * 8];
            acc[g] = __builtin_amdgcn_mfma_f32_16x16x32_f16(af, bf, acc[g], 0, 0, 0);
        }
    }

    // D: row(node) = quad*4 + r, col(feat) = g*16 + m
#pragma unroll
    for (int r = 0; r < 4; ++r) {
        int n = wv * 16 + quad * 4 + r;
        long gn = nbase + n;
        if (gn < N_NODES) {
            float di = dinv[gn];
#pragma unroll
            for (int g = 0; g < 4; ++g)
                out[gn * HIDDEN + g * 16 + m] = __float2half(acc[g][r] * di);
        }
    }
}

// add one fp16 row-octet (int4 = 8 halves) into fp32 accumulators
__device__ __forceinline__ void acc_row8(float* a, int4 rv) {
    float2 f;
    f = __half22float2(*(__half2*)&rv.x); a[0] += f.x; a[1] += f.y;
    f = __half22float2(*(__half2*)&rv.y); a[2] += f.x; a[3] += f.y;
    f = __half22float2(*(__half2*)&rv.z); a[4] += f.x; a[5] += f.y;
    f = __half22float2(*(__half2*)&rv.w); a[6] += f.x; a[7] += f.y;
}

// ---- feature-half-split aggregation with XCD-steered halves ----
// out[d, half*32 .. +31] = relu( dinv[d] * (sum_e h'[src] + h'[d]) + b )[half]
// Working set per half = 50000*32*2B = 3.2MB < 4MB per-XCD L2. blockIdx%8
// round-robins across XCDs: XCDs 0-3 take half 0, XCDs 4-7 take half 1, so
// each XCD's L2 only ever sees one 3.2MB half (64B-line aligned: half = one
// cache line per row). Heuristic only — wrong mapping costs speed, not
// correctness. One wave per (node, half): lane = {edge slot e16 = lane>>2,
// feature quad q = lane&3}. Mean degree 16 -> one predicated batch.
__global__ void k_gather(const __half* __restrict__ h, const int* __restrict__ csr,
                         const int2* __restrict__ rse, const float* __restrict__ dinv,
                         const float* __restrict__ bias, __half* __restrict__ out) {
    int b = blockIdx.x;                    // 25000 blocks = 8 * 3125
    int grp = b & 3;
    int half = (b >> 2) & 1;               // xcd = b&7; 0-3 -> half0, 4-7 -> half1
    int nodeblk = (b >> 3) * 4 + grp;      // 0..12499, each half covers all nodes
    int t = threadIdx.x;
    int node = __builtin_amdgcn_readfirstlane(nodeblk * 4 + (t >> 6));
    int lane = t & 63;
    int e16 = lane >> 2;   // edge slot 0..15
    int q = lane & 3;      // feature quad within half
    int fb = half * 32 + q * 8;            // feature base (8 halves = 16B)
    int2 se = rse[node];
    int r0 = se.x, r1 = se.x + se.y;
    float dd = dinv[node];

    float a[8] = {0.f, 0.f, 0.f, 0.f, 0.f, 0.f, 0.f, 0.f};
    if (e16 == 0)  // self-loop row counted once (lanes 0..3 cover q=0..3)
        acc_row8(a, *(const int4*)&h[(long)node * HIDDEN + fb]);

    // first 16 edge slots, predicated (covers deg<=16 nodes entirely)
    int i0 = r0 + e16;
    if (i0 < r1) {
        int sA = csr[i0];
        acc_row8(a, *(const int4*)&h[(long)sA * HIDDEN + fb]);
    }
    // rare tail: deg > 16 (P small for mean-16 uniform graph)
    for (int j = r0 + 16; j < r1; j += 16) {
        int i2 = j + e16;
        if (i2 < r1) {
            int sB = csr[i2];
            acc_row8(a, *(const int4*)&h[(long)sB * HIDDEN + fb]);
        }
    }
    // reduce across the 16 edge slots (upper 4 lane bits)
#pragma unroll
    for (int off = 4; off < 64; off <<= 1)
#pragma unroll
        for (int i = 0; i < 8; ++i) a[i] += __shfl_xor(a[i], off, 64);

    if (e16 == 0) {
        float4 b0 = *(const float4*)&bias[fb];
        float4 b1 = *(const float4*)&bias[fb + 4];
        float r[8];
        r[0] = fmaxf(fmaf(a[0], dd, b0.x), 0.f);
        r[1] = fmaxf(fmaf(a[1], dd, b0.y), 0.f);
        r[2] = fmaxf(fmaf(a[2], dd, b0.z), 0.f);
        r[3] = fmaxf(fmaf(a[3], dd, b0.w), 0.f);
        r[4] = fmaxf(fmaf(a[4], dd, b1.x), 0.f);
        r[5] = fmaxf(fmaf(a[5], dd, b1.y), 0.f);
        r[6] = fmaxf(fmaf(a[6], dd, b1.z), 0.f);
        r[7] = fmaxf(fmaf(a[7], dd, b1.w), 0.f);
        __half2 h0 = __floats2half2_rn(r[0], r[1]);
        __half2 h1 = __floats2half2_rn(r[2], r[3]);
        __half2 h2 = __floats2half2_rn(r[4], r[5]);
        __half2 h3 = __floats2half2_rn(r[6], r[7]);
        int4 o;
        o.x = *(int*)&h0; o.y = *(int*)&h1; o.z = *(int*)&h2; o.w = *(int*)&h3;
        *(int4*)&out[(long)node * HIDDEN + fb] = o;
    }
}

// ---- logits = h @ Wout + bout, softmax over 16 classes (fp32 math) ----
__global__ void k_out(const __half* __restrict__ h, const float* __restrict__ w,
                      const float* __restrict__ b, float* __restrict__ out) {
    __shared__ float Ws[HIDDEN * N_CLASSES];
    __shared__ float bs[N_CLASSES];
    int tid = threadIdx.x;
    for (int i = tid; i < HIDDEN * N_CLASSES; i += 256) Ws[i] = w[i];
    if (tid < N_CLASSES) bs[tid] = b[tid];
    __syncthreads();
    int node = blockIdx.x * 16 + (tid >> 4);
    int c = tid & 15;
    const __half* hr = h + (long)node * HIDDEN;
    float acc = bs[c];
#pragma unroll
    for (int k = 0; k < HIDDEN; ++k)
        acc = fmaf(__half2float(hr[k]), Ws[k * N_CLASSES + c], acc);
    float m = acc;
#pragma unroll
    for (int off = 8; off; off >>= 1) m = fmaxf(m, __shfl_xor(m, off, 16));
    float ex = expf(acc - m);
    float s = ex;
#pragma unroll
    for (int off = 8; off; off >>= 1) s += __shfl_xor(s, off, 16);
    out[(long)node * N_CLASSES + c] = ex / s;
}

extern "C" void kernel_launch(void* const* d_in, const int* in_sizes, int n_in,
                              void* d_out, int out_size, void* d_ws, size_t ws_size,
                              hipStream_t stream) {
    const float* x    = (const float*)d_in[0];
    const int*   ei   = (const int*)d_in[1];
    const float* W1   = (const float*)d_in[2];
    const float* b1   = (const float*)d_in[3];
    const float* W2   = (const float*)d_in[4];
    const float* b2   = (const float*)d_in[5];
    const float* Wout = (const float*)d_in[6];
    const float* bout = (const float*)d_in[7];
    float* out = (float*)d_out;

    char* ws = (char*)d_ws;
    int2*   rse     = (int2*)ws;                       ws += 400128;   // 50000 int2
    float*  dinv    = (float*)ws;                      ws += 200192;   // 50000 f32
    int*    tileCur = (int*)ws;                        ws += 1024;
    int*    csr     = (int*)ws;                        ws += (size_t)NBLK_NODE * TCAP * 4;  // 6.42 MB
    char*   slotA   = ws;                              ws += 6553600;  // max(binned, bufA)
    __half* bufB    = (__half*)ws;
    int*    binned  = (int*)slotA;        // dies before k_mm<128> writes bufA
    __half* bufA    = (__half*)slotA;

    const int NB_MM = (N_NODES + 63) / 64;        // 782
    const int NB_E16 = (N_EDGES + 4095) / 4096;   // 196
    const int NB_GATHER = 2 * (N_NODES / 4) / 4 * 4;  // 25000 = 8*3125 (2 halves)

    // ---- CSR build: bucketed partition -> counting sort (+deg/dinv/rse) ----
    k_init<<<1, 256, 0, stream>>>(tileCur);
    k_part<<<NB_E16, 256, 0, stream>>>(ei, tileCur, binned);
    k_finesort<<<NBLK_NODE, 256, 0, stream>>>(binned, tileCur, csr, rse, dinv);

    // ---- layer 1 (mm output pre-scaled by dinv; gather is a pure row-sum) ----
    k_mm<N_FEAT, float><<<NB_MM, 256, 0, stream>>>(x, W1, dinv, bufA);
    k_gather<<<NB_GATHER, 256, 0, stream>>>(bufA, csr, rse, dinv, b1, bufB);

    // ---- layer 2 ----
    k_mm<HIDDEN, __half><<<NB_MM, 256, 0, stream>>>(bufB, W2, dinv, bufA);
    k_gather<<<NB_GATHER, 256, 0, stream>>>(bufA, csr, rse, dinv, b2, bufB);

    // ---- output layer + softmax ----
    k_out<<<N_NODES / 16, 256, 0, stream>>>(bufB, Wout, bout, out);
}

// Round 3
// 191.408 us; speedup vs baseline: 1.0760x; 1.0760x over previous
//
#include <hip/hip_runtime.h>
#include <hip/hip_fp16.h>

#define N_NODES 50000
#define N_EDGES 800000
#define N_FEAT 128
#define HIDDEN 64
#define N_CLASSES 16
#define NBLK_NODE 196   // number of 256-node dst tiles (ceil(50000/256))
#define TCAP 8192       // per-tile bucket capacity (recs); mean 4083, sigma ~64
#define PLANE (N_NODES * 32)  // fp16 elems per 32-feature plane (3.2 MB)

typedef _Float16 f16x8 __attribute__((ext_vector_type(8)));
typedef float f32x4 __attribute__((ext_vector_type(4)));

// tileCur[t] = t*TCAP (bucket base cursors)
__global__ void k_init(int* __restrict__ tileCur) {
    int tid = threadIdx.x;
    if (tid < NBLK_NODE) tileCur[tid] = tid * TCAP;
}

// Partition edges into 196 fixed-capacity dst-tile buckets. Per block: LDS
// histogram, ONE global atomic per (block,tile) reserves a contiguous sub-run
// -> block-owned 4B record stores merge in L2. record: src | dstLocal<<16
__global__ __launch_bounds__(256) void k_part(const int* __restrict__ ei,
                                              int* __restrict__ tileCur,
                                              int* __restrict__ binned) {
    __shared__ int cnt[NBLK_NODE], base[NBLK_NODE], cur[NBLK_NODE];
    int tid = threadIdx.x;
    int start = blockIdx.x * 4096;
    if (tid < NBLK_NODE) cnt[tid] = 0;
    __syncthreads();
    int s[16], d[16];
#pragma unroll
    for (int u = 0; u < 4; ++u) {
        int e0 = start + u * 1024 + tid * 4;
        if (e0 + 4 <= N_EDGES) {
            int4 s4 = *(const int4*)&ei[e0];
            int4 d4 = *(const int4*)&ei[N_EDGES + e0];
            s[u * 4 + 0] = s4.x; s[u * 4 + 1] = s4.y; s[u * 4 + 2] = s4.z; s[u * 4 + 3] = s4.w;
            d[u * 4 + 0] = d4.x; d[u * 4 + 1] = d4.y; d[u * 4 + 2] = d4.z; d[u * 4 + 3] = d4.w;
#pragma unroll
            for (int q = 0; q < 4; ++q) atomicAdd(&cnt[d[u * 4 + q] >> 8], 1);
        } else {
#pragma unroll
            for (int q = 0; q < 4; ++q) {
                int e = e0 + q;
                if (e < N_EDGES) {
                    s[u * 4 + q] = ei[e];
                    d[u * 4 + q] = ei[N_EDGES + e];
                    atomicAdd(&cnt[d[u * 4 + q] >> 8], 1);
                } else s[u * 4 + q] = -1;
            }
        }
    }
    __syncthreads();
    if (tid < NBLK_NODE) {
        base[tid] = atomicAdd(&tileCur[tid], cnt[tid]);
        cur[tid] = 0;
    }
    __syncthreads();
#pragma unroll
    for (int u = 0; u < 16; ++u) {
        if (s[u] < 0) continue;
        int t = d[u] >> 8;
        int r = atomicAdd(&cur[t], 1);
        int p = base[t] + r;
        if (p < (t + 1) * TCAP)  // bucket-bound guard (never hit for uniform input)
            binned[p] = s[u] | ((d[u] & 255) << 16);
    }
}

// Per-tile counting sort (bucketed layout) — round-0 verbatim (measured-good).
// Also derives degree -> dinv and per-node {start,count} rse.
__global__ __launch_bounds__(256) void k_finesort(const int* __restrict__ binned,
                                                  const int* __restrict__ tileCur,
                                                  int* __restrict__ csr,
                                                  int2* __restrict__ rse,
                                                  float* __restrict__ dinv) {
    __shared__ int stage[TCAP];
    __shared__ int sc[256];
    __shared__ int cnt256[256];
    __shared__ int nodeOff[256];
    int tid = threadIdx.x;
    int tb = blockIdx.x;
    int beg = tb * TCAP;
    int m = tileCur[tb] - beg;
    if (m > TCAP) m = TCAP;
    cnt256[tid] = 0;
    __syncthreads();
    const int4* b4 = (const int4*)(binned + beg);
    int nv = m >> 2;
    for (int i = tid; i < nv; i += 256) {
        int4 r = b4[i];
        atomicAdd(&cnt256[(r.x >> 16) & 255], 1);
        atomicAdd(&cnt256[(r.y >> 16) & 255], 1);
        atomicAdd(&cnt256[(r.z >> 16) & 255], 1);
        atomicAdd(&cnt256[(r.w >> 16) & 255], 1);
    }
    for (int i = (m & ~3) + tid; i < m; i += 256)
        atomicAdd(&cnt256[(binned[beg + i] >> 16) & 255], 1);
    __syncthreads();
    int myc = cnt256[tid];
    sc[tid] = myc;
    __syncthreads();
#pragma unroll
    for (int off = 1; off < 256; off <<= 1) {
        int t = (tid >= off) ? sc[tid - off] : 0;
        __syncthreads();
        sc[tid] += t;
        __syncthreads();
    }
    int off0 = sc[tid] - myc;
    nodeOff[tid] = off0;
    int gnode = tb * 256 + tid;
    if (gnode < N_NODES) {
        dinv[gnode] = rsqrtf((float)myc + 1.0f);  // deg = in-edges + self-loop
        rse[gnode] = make_int2(beg + off0, myc);
    }
    cnt256[tid] = 0;
    __syncthreads();
    for (int i = tid; i < nv; i += 256) {
        int4 r = b4[i];
        int rr;
        rr = atomicAdd(&cnt256[(r.x >> 16) & 255], 1); stage[nodeOff[(r.x >> 16) & 255] + rr] = r.x & 0xFFFF;
        rr = atomicAdd(&cnt256[(r.y >> 16) & 255], 1); stage[nodeOff[(r.y >> 16) & 255] + rr] = r.y & 0xFFFF;
        rr = atomicAdd(&cnt256[(r.z >> 16) & 255], 1); stage[nodeOff[(r.z >> 16) & 255] + rr] = r.z & 0xFFFF;
        rr = atomicAdd(&cnt256[(r.w >> 16) & 255], 1); stage[nodeOff[(r.w >> 16) & 255] + rr] = r.w & 0xFFFF;
    }
    for (int i = (m & ~3) + tid; i < m; i += 256) {
        int rec = binned[beg + i];
        int dl = (rec >> 16) & 255;
        int rr = atomicAdd(&cnt256[dl], 1);
        stage[nodeOff[dl] + rr] = rec & 0xFFFF;
    }
    __syncthreads();
    int4* c4 = (int4*)(csr + beg);
    for (int i = tid; i < nv; i += 256) c4[i] = ((const int4*)stage)[i];
    for (int i = (m & ~3) + tid; i < m; i += 256) csr[beg + i] = stage[i];
}

// ---- MFMA GEMM: out[n,f] = (A @ W)[n,f] * dinv[n], fp16 PLANAR out ----
// Output/fp16-input layout: plane p (p = f>>5) holds feats p*32..p*32+31 of
// all nodes contiguously (50000 x 32 fp16 = 3.2 MB < 4 MB per-XCD L2).
// Block = 256 thr = 4 waves = 64 nodes; wave w covers nodes nbase+16w..+15.
// mfma_f32_16x16x32_f16; A-frag A[m=lane&15][k=quad*8+j]; B-frag
// B[k=quad*8+j][n=lane&15]; D row=quad*4+reg, col=lane&15 (verified layouts).
// A and W staged k-contiguous in LDS, stride K+8 halves (2-way banks = free).
template <int K, typename TIn>
__global__ __launch_bounds__(256) void k_mm(const TIn* __restrict__ a,
                                            const float* __restrict__ w,
                                            const float* __restrict__ dinv,
                                            __half* __restrict__ out) {
    constexpr int LDK = K + 8;
    __shared__ __align__(16) __half A_lds[64 * LDK];
    __shared__ __align__(16) __half Wt_lds[64 * LDK];
    int tid = threadIdx.x;
    long nbase = (long)blockIdx.x * 64;

    // stage W transposed: w[k*64+f] (fp32) -> Wt_lds[f][k] (fp16)
    for (int i = tid; i < K * 16; i += 256) {
        int k = (i * 4) >> 6;
        int f0 = (i * 4) & 63;
        float4 v = *(const float4*)&w[i * 4];
        Wt_lds[(f0 + 0) * LDK + k] = __float2half(v.x);
        Wt_lds[(f0 + 1) * LDK + k] = __float2half(v.y);
        Wt_lds[(f0 + 2) * LDK + k] = __float2half(v.z);
        Wt_lds[(f0 + 3) * LDK + k] = __float2half(v.w);
    }
    // stage A rows -> A_lds[n][k] fp16 (8-elem chunks)
    for (int i = tid; i < 64 * K / 8; i += 256) {
        int n = (i * 8) / K;
        int k0 = (i * 8) % K;
        long gn = nbase + n;
        if constexpr (sizeof(TIn) == 4) {
            // layer-1 input: row-major fp32 x[n][128]
            float4 v0, v1;
            if (gn < N_NODES) {
                v0 = *(const float4*)&a[gn * K + k0];
                v1 = *(const float4*)&a[gn * K + k0 + 4];
            } else {
                v0 = make_float4(0.f, 0.f, 0.f, 0.f);
                v1 = v0;
            }
            __half2* dst = (__half2*)&A_lds[n * LDK + k0];
            dst[0] = __floats2half2_rn(v0.x, v0.y);
            dst[1] = __floats2half2_rn(v0.z, v0.w);
            dst[2] = __floats2half2_rn(v1.x, v1.y);
            dst[3] = __floats2half2_rn(v1.z, v1.w);
        } else {
            // layer-2 input: PLANAR fp16 (plane k0>>5, col k0&31)
            const __half* ap = (const __half*)a + (long)(k0 >> 5) * PLANE;
            int4 v = (gn < N_NODES) ? *(const int4*)&ap[gn * 32 + (k0 & 31)]
                                    : make_int4(0, 0, 0, 0);
            *(int4*)&A_lds[n * LDK + k0] = v;
        }
    }
    __syncthreads();

    int wv = tid >> 6;
    int lane = tid & 63;
    int m = lane & 15;      // A row within wave tile / D col
    int quad = lane >> 4;   // 0..3
    const __half* Arow = &A_lds[(wv * 16 + m) * LDK + quad * 8];
    f32x4 acc[4] = {};      // 4 feature col-tiles of 16
#pragma unroll
    for (int t = 0; t < K; t += 32) {
        f16x8 af = *(const f16x8*)(const void*)&Arow[t];
#pragma unroll
        for (int g = 0; g < 4; ++g) {
            f16x8 bf = *(const f16x8*)(const void*)&Wt_lds[(g * 16 + m) * LDK + t + quad * 8];
            acc[g] = __builtin_amdgcn_mfma_f32_16x16x32_f16(af, bf, acc[g], 0, 0, 0);
        }
    }

    // D: row(node) = quad*4 + r, col(feat) = g*16 + m -> plane g>>1, col (g&1)*16+m
#pragma unroll
    for (int r = 0; r < 4; ++r) {
        int n = wv * 16 + quad * 4 + r;
        long gn = nbase + n;
        if (gn < N_NODES) {
            float di = dinv[gn];
#pragma unroll
            for (int g = 0; g < 4; ++g)
                out[(long)(g >> 1) * PLANE + gn * 32 + (g & 1) * 16 + m] =
                    __float2half(acc[g][r] * di);
        }
    }
}

// add one fp16 quad (int2 = 4 halves) into fp32 accumulators
__device__ __forceinline__ void acc_row4(float* a, int2 rv) {
    float2 f;
    f = __half22float2(*(__half2*)&rv.x); a[0] += f.x; a[1] += f.y;
    f = __half22float2(*(__half2*)&rv.y); a[2] += f.x; a[3] += f.y;
}

// ---- PLANAR aggregation, XCD-steered halves, round-0 loop structure ----
// out[d, half] = relu( dinv[d] * (sum_e h'[src] + h'[d]) + b )[half-plane]
// Reuse set per XCD = one 3.2MB plane + ~0.8MB csr slice < 4MB L2.
// blockIdx%8 = XCD (round-robin heuristic): XCDs 0-3 take plane 0, 4-7 plane 1.
// One wave per (node, half). lane = {edge slot e8 = lane>>3, quad q = lane&7};
// 8 lanes x int2 (8B) cover exactly one 64B half-row. Two independent loads
// in flight in the main loop (round-0 ILP shape).
__global__ void k_gather(const __half* __restrict__ h, const int* __restrict__ csr,
                         const int2* __restrict__ rse, const float* __restrict__ dinv,
                         const float* __restrict__ bias, __half* __restrict__ out) {
    int b = blockIdx.x;                  // 25000 = 8 * 3125
    int x = b & 7;                       // XCD id under round-robin dispatch
    int half = x >> 2;                   // 0-3 -> plane0, 4-7 -> plane1
    int nb = (b >> 3) * 4 + (x & 3);     // node-block 0..12499 within this half
    int t = threadIdx.x;
    int node = __builtin_amdgcn_readfirstlane(nb * 4 + (t >> 6));
    int lane = t & 63;
    int e8 = lane >> 3;   // edge slot 0..7
    int q = lane & 7;     // feature quad within the half (4 halves = 8B)
    const __half* hp = h + (long)half * PLANE;
    int2 se = rse[node];
    int r0 = se.x, r1 = se.x + se.y;
    float dd = dinv[node];

    float a[4] = {0.f, 0.f, 0.f, 0.f};
    if (e8 == 0)  // self-loop row counted once (lanes 0..7 cover the half)
        acc_row4(a, *(const int2*)&hp[(long)node * 32 + q * 4]);

    int j = r0;
    while (j + 16 <= r1) {  // 16 edges: 2 independent 8-row batches in flight
        int sA = csr[j + e8];
        int sB = csr[j + 8 + e8];
        int2 rA = *(const int2*)&hp[(long)sA * 32 + q * 4];
        int2 rB = *(const int2*)&hp[(long)sB * 32 + q * 4];
        acc_row4(a, rA);
        acc_row4(a, rB);
        j += 16;
    }
    if (j + 8 <= r1) {
        int sA = csr[j + e8];
        acc_row4(a, *(const int2*)&hp[(long)sA * 32 + q * 4]);
        j += 8;
    }
    int rem = r1 - j;  // 0..7
    if (e8 < rem) {
        int sA = csr[j + e8];
        acc_row4(a, *(const int2*)&hp[(long)sA * 32 + q * 4]);
    }
    // reduce across the 8 edge slots
#pragma unroll
    for (int off = 8; off < 64; off <<= 1)
#pragma unroll
        for (int i = 0; i < 4; ++i) a[i] += __shfl_xor(a[i], off, 64);

    if (e8 == 0) {
        float4 bv = *(const float4*)&bias[half * 32 + q * 4];
        float r0f = fmaxf(fmaf(a[0], dd, bv.x), 0.f);
        float r1f = fmaxf(fmaf(a[1], dd, bv.y), 0.f);
        float r2f = fmaxf(fmaf(a[2], dd, bv.z), 0.f);
        float r3f = fmaxf(fmaf(a[3], dd, bv.w), 0.f);
        __half2 h0 = __floats2half2_rn(r0f, r1f);
        __half2 h1 = __floats2half2_rn(r2f, r3f);
        int2 o;
        o.x = *(int*)&h0; o.y = *(int*)&h1;
        *(int2*)&out[(long)half * PLANE + (long)node * 32 + q * 4] = o;
    }
}

// ---- logits = h @ Wout + bout, softmax over 16 classes (fp32 math) ----
// h is planar: plane0 = feats 0-31, plane1 = feats 32-63.
__global__ void k_out(const __half* __restrict__ h, const float* __restrict__ w,
                      const float* __restrict__ b, float* __restrict__ out) {
    __shared__ float Ws[HIDDEN * N_CLASSES];
    __shared__ float bs[N_CLASSES];
    int tid = threadIdx.x;
    for (int i = tid; i < HIDDEN * N_CLASSES; i += 256) Ws[i] = w[i];
    if (tid < N_CLASSES) bs[tid] = b[tid];
    __syncthreads();
    int node = blockIdx.x * 16 + (tid >> 4);
    int c = tid & 15;
    const __half* hr0 = h + (long)node * 32;
    const __half* hr1 = h + (long)PLANE + (long)node * 32;
    float acc = bs[c];
#pragma unroll
    for (int k = 0; k < 32; ++k)
        acc = fmaf(__half2float(hr0[k]), Ws[k * N_CLASSES + c], acc);
#pragma unroll
    for (int k = 0; k < 32; ++k)
        acc = fmaf(__half2float(hr1[k]), Ws[(k + 32) * N_CLASSES + c], acc);
    float m = acc;
#pragma unroll
    for (int off = 8; off; off >>= 1) m = fmaxf(m, __shfl_xor(m, off, 16));
    float ex = expf(acc - m);
    float s = ex;
#pragma unroll
    for (int off = 8; off; off >>= 1) s += __shfl_xor(s, off, 16);
    out[(long)node * N_CLASSES + c] = ex / s;
}

extern "C" void kernel_launch(void* const* d_in, const int* in_sizes, int n_in,
                              void* d_out, int out_size, void* d_ws, size_t ws_size,
                              hipStream_t stream) {
    const float* x    = (const float*)d_in[0];
    const int*   ei   = (const int*)d_in[1];
    const float* W1   = (const float*)d_in[2];
    const float* b1   = (const float*)d_in[3];
    const float* W2   = (const float*)d_in[4];
    const float* b2   = (const float*)d_in[5];
    const float* Wout = (const float*)d_in[6];
    const float* bout = (const float*)d_in[7];
    float* out = (float*)d_out;

    char* ws = (char*)d_ws;
    int2*   rse     = (int2*)ws;                       ws += 400128;   // 50000 int2
    float*  dinv    = (float*)ws;                      ws += 200192;   // 50000 f32
    int*    tileCur = (int*)ws;                        ws += 1024;
    int*    csr     = (int*)ws;                        ws += (size_t)NBLK_NODE * TCAP * 4;  // 6.42 MB
    char*   slotA   = ws;                              ws += 6553600;  // max(binned, bufA 2 planes)
    __half* bufB    = (__half*)ws;                     // 2 planes, 6.4 MB
    int*    binned  = (int*)slotA;        // dies before k_mm<128> writes bufA
    __half* bufA    = (__half*)slotA;

    const int NB_MM = (N_NODES + 63) / 64;        // 782
    const int NB_E16 = (N_EDGES + 4095) / 4096;   // 196
    const int NB_GATHER = 2 * (N_NODES / 4);      // 25000 = 2 halves x 12500

    // ---- CSR build: bucketed partition -> counting sort (+deg/dinv/rse) ----
    k_init<<<1, 256, 0, stream>>>(tileCur);
    k_part<<<NB_E16, 256, 0, stream>>>(ei, tileCur, binned);
    k_finesort<<<NBLK_NODE, 256, 0, stream>>>(binned, tileCur, csr, rse, dinv);

    // ---- layer 1 (mm output pre-scaled by dinv; gather is a pure row-sum) ----
    k_mm<N_FEAT, float><<<NB_MM, 256, 0, stream>>>(x, W1, dinv, bufA);
    k_gather<<<NB_GATHER, 256, 0, stream>>>(bufA, csr, rse, dinv, b1, bufB);

    // ---- layer 2 ----
    k_mm<HIDDEN, __half><<<NB_MM, 256, 0, stream>>>(bufB, W2, dinv, bufA);
    k_gather<<<NB_GATHER, 256, 0, stream>>>(bufA, csr, rse, dinv, b2, bufB);

    // ---- output layer + softmax ----
    k_out<<<N_NODES / 16, 256, 0, stream>>>(bufB, Wout, bout, out);
}

// Round 4
// 164.732 us; speedup vs baseline: 1.2503x; 1.1619x over previous
//
#include <hip/hip_runtime.h>
#include <hip/hip_fp16.h>

#define N_NODES 50000
#define N_EDGES 800000
#define N_FEAT 128
#define HIDDEN 64
#define N_CLASSES 16
#define NBLK_NODE 196   // number of 256-node dst tiles (ceil(50000/256))
#define TCAP 8192       // per-tile bucket capacity (recs); mean 4083, sigma ~64

typedef _Float16 f16x8 __attribute__((ext_vector_type(8)));
typedef float f32x4 __attribute__((ext_vector_type(4)));

// tileCur[t] = t*TCAP (bucket base cursors)
__global__ void k_init(int* __restrict__ tileCur) {
    int tid = threadIdx.x;
    if (tid < NBLK_NODE) tileCur[tid] = tid * TCAP;
}

// Partition edges into 196 fixed-capacity dst-tile buckets. Per block: LDS
// histogram, ONE global atomic per (block,tile) reserves a contiguous sub-run
// -> block-owned 4B record stores merge in L2. record: src | dstLocal<<16
__global__ __launch_bounds__(256) void k_part(const int* __restrict__ ei,
                                              int* __restrict__ tileCur,
                                              int* __restrict__ binned) {
    __shared__ int cnt[NBLK_NODE], base[NBLK_NODE], cur[NBLK_NODE];
    int tid = threadIdx.x;
    int start = blockIdx.x * 4096;
    if (tid < NBLK_NODE) cnt[tid] = 0;
    __syncthreads();
    int s[16], d[16];
#pragma unroll
    for (int u = 0; u < 4; ++u) {
        int e0 = start + u * 1024 + tid * 4;
        if (e0 + 4 <= N_EDGES) {
            int4 s4 = *(const int4*)&ei[e0];
            int4 d4 = *(const int4*)&ei[N_EDGES + e0];
            s[u * 4 + 0] = s4.x; s[u * 4 + 1] = s4.y; s[u * 4 + 2] = s4.z; s[u * 4 + 3] = s4.w;
            d[u * 4 + 0] = d4.x; d[u * 4 + 1] = d4.y; d[u * 4 + 2] = d4.z; d[u * 4 + 3] = d4.w;
#pragma unroll
            for (int q = 0; q < 4; ++q) atomicAdd(&cnt[d[u * 4 + q] >> 8], 1);
        } else {
#pragma unroll
            for (int q = 0; q < 4; ++q) {
                int e = e0 + q;
                if (e < N_EDGES) {
                    s[u * 4 + q] = ei[e];
                    d[u * 4 + q] = ei[N_EDGES + e];
                    atomicAdd(&cnt[d[u * 4 + q] >> 8], 1);
                } else s[u * 4 + q] = -1;
            }
        }
    }
    __syncthreads();
    if (tid < NBLK_NODE) {
        base[tid] = atomicAdd(&tileCur[tid], cnt[tid]);
        cur[tid] = 0;
    }
    __syncthreads();
#pragma unroll
    for (int u = 0; u < 16; ++u) {
        if (s[u] < 0) continue;
        int t = d[u] >> 8;
        int r = atomicAdd(&cur[t], 1);
        int p = base[t] + r;
        if (p < (t + 1) * TCAP)  // bucket-bound guard (never hit for uniform input)
            binned[p] = s[u] | ((d[u] & 255) << 16);
    }
}

// ---- finesort body (round-0 verbatim): per-tile counting sort in LDS ----
// smem layout: stage[TCAP] | sc[256] | cnt256[256] | nodeOff[256]  = 35840 B
__device__ __forceinline__ void finesort_body(int tb, const int* __restrict__ binned,
                                              const int* __restrict__ tileCur,
                                              int* __restrict__ csr,
                                              int2* __restrict__ rse,
                                              float* __restrict__ dinv, char* smem) {
    int* stage   = (int*)smem;
    int* sc      = stage + TCAP;
    int* cnt256  = sc + 256;
    int* nodeOff = cnt256 + 256;
    int tid = threadIdx.x;
    int beg = tb * TCAP;
    int m = tileCur[tb] - beg;
    if (m > TCAP) m = TCAP;
    cnt256[tid] = 0;
    __syncthreads();
    const int4* b4 = (const int4*)(binned + beg);
    int nv = m >> 2;
    for (int i = tid; i < nv; i += 256) {
        int4 r = b4[i];
        atomicAdd(&cnt256[(r.x >> 16) & 255], 1);
        atomicAdd(&cnt256[(r.y >> 16) & 255], 1);
        atomicAdd(&cnt256[(r.z >> 16) & 255], 1);
        atomicAdd(&cnt256[(r.w >> 16) & 255], 1);
    }
    for (int i = (m & ~3) + tid; i < m; i += 256)
        atomicAdd(&cnt256[(binned[beg + i] >> 16) & 255], 1);
    __syncthreads();
    int myc = cnt256[tid];
    sc[tid] = myc;
    __syncthreads();
#pragma unroll
    for (int off = 1; off < 256; off <<= 1) {
        int t = (tid >= off) ? sc[tid - off] : 0;
        __syncthreads();
        sc[tid] += t;
        __syncthreads();
    }
    int off0 = sc[tid] - myc;
    nodeOff[tid] = off0;
    int gnode = tb * 256 + tid;
    if (gnode < N_NODES) {
        dinv[gnode] = rsqrtf((float)myc + 1.0f);  // deg = in-edges + self-loop
        rse[gnode] = make_int2(beg + off0, myc);
    }
    cnt256[tid] = 0;
    __syncthreads();
    for (int i = tid; i < nv; i += 256) {
        int4 r = b4[i];
        int rr;
        rr = atomicAdd(&cnt256[(r.x >> 16) & 255], 1); stage[nodeOff[(r.x >> 16) & 255] + rr] = r.x & 0xFFFF;
        rr = atomicAdd(&cnt256[(r.y >> 16) & 255], 1); stage[nodeOff[(r.y >> 16) & 255] + rr] = r.y & 0xFFFF;
        rr = atomicAdd(&cnt256[(r.z >> 16) & 255], 1); stage[nodeOff[(r.z >> 16) & 255] + rr] = r.z & 0xFFFF;
        rr = atomicAdd(&cnt256[(r.w >> 16) & 255], 1); stage[nodeOff[(r.w >> 16) & 255] + rr] = r.w & 0xFFFF;
    }
    for (int i = (m & ~3) + tid; i < m; i += 256) {
        int rec = binned[beg + i];
        int dl = (rec >> 16) & 255;
        int rr = atomicAdd(&cnt256[dl], 1);
        stage[nodeOff[dl] + rr] = rec & 0xFFFF;
    }
    __syncthreads();
    int4* c4 = (int4*)(csr + beg);
    for (int i = tid; i < nv; i += 256) c4[i] = ((const int4*)stage)[i];
    for (int i = (m & ~3) + tid; i < m; i += 256) csr[beg + i] = stage[i];
}

// ---- MFMA GEMM body: out[n,f] = (A @ W)[n,f], fp16 out, NO dinv scale ----
// (dinv[src] scaling moved into the gather -> mm1 is independent of CSR build)
// Block = 256 thr = 4 waves = 64 nodes. Layouts as in round 0 (verified).
// smem: A_lds[64*(K+8)] halves | Wt_lds[64*(K+8)] halves
template <int K, typename TIn>
__device__ __forceinline__ void mm_body(int bx, const TIn* __restrict__ a,
                                        const float* __restrict__ w,
                                        __half* __restrict__ out, char* smem) {
    constexpr int LDK = K + 8;
    __half* A_lds  = (__half*)smem;
    __half* Wt_lds = A_lds + 64 * LDK;
    int tid = threadIdx.x;
    long nbase = (long)bx * 64;

    // stage W transposed: w[k*64+f] (fp32) -> Wt_lds[f][k] (fp16)
    for (int i = tid; i < K * 16; i += 256) {
        int k = (i * 4) >> 6;
        int f0 = (i * 4) & 63;
        float4 v = *(const float4*)&w[i * 4];
        Wt_lds[(f0 + 0) * LDK + k] = __float2half(v.x);
        Wt_lds[(f0 + 1) * LDK + k] = __float2half(v.y);
        Wt_lds[(f0 + 2) * LDK + k] = __float2half(v.z);
        Wt_lds[(f0 + 3) * LDK + k] = __float2half(v.w);
    }
    // stage A rows -> A_lds[n][k] fp16 (8-elem chunks)
    for (int i = tid; i < 64 * K / 8; i += 256) {
        int n = (i * 8) / K;
        int k0 = (i * 8) % K;
        long gn = nbase + n;
        if constexpr (sizeof(TIn) == 4) {
            float4 v0, v1;
            if (gn < N_NODES) {
                v0 = *(const float4*)&a[gn * K + k0];
                v1 = *(const float4*)&a[gn * K + k0 + 4];
            } else {
                v0 = make_float4(0.f, 0.f, 0.f, 0.f);
                v1 = v0;
            }
            __half2* dst = (__half2*)&A_lds[n * LDK + k0];
            dst[0] = __floats2half2_rn(v0.x, v0.y);
            dst[1] = __floats2half2_rn(v0.z, v0.w);
            dst[2] = __floats2half2_rn(v1.x, v1.y);
            dst[3] = __floats2half2_rn(v1.z, v1.w);
        } else {
            int4 v = (gn < N_NODES) ? *(const int4*)&a[gn * K + k0]
                                    : make_int4(0, 0, 0, 0);
            *(int4*)&A_lds[n * LDK + k0] = v;
        }
    }
    __syncthreads();

    int wv = tid >> 6;
    int lane = tid & 63;
    int m = lane & 15;      // A row within wave tile / D col
    int quad = lane >> 4;   // 0..3
    const __half* Arow = &A_lds[(wv * 16 + m) * LDK + quad * 8];
    f32x4 acc[4] = {};      // 4 feature col-tiles of 16
#pragma unroll
    for (int t = 0; t < K; t += 32) {
        f16x8 af = *(const f16x8*)(const void*)&Arow[t];
#pragma unroll
        for (int g = 0; g < 4; ++g) {
            f16x8 bf = *(const f16x8*)(const void*)&Wt_lds[(g * 16 + m) * LDK + t + quad * 8];
            acc[g] = __builtin_amdgcn_mfma_f32_16x16x32_f16(af, bf, acc[g], 0, 0, 0);
        }
    }

    // D: row(node) = quad*4 + r, col(feat) = g*16 + m
#pragma unroll
    for (int r = 0; r < 4; ++r) {
        int n = wv * 16 + quad * 4 + r;
        long gn = nbase + n;
        if (gn < N_NODES) {
#pragma unroll
            for (int g = 0; g < 4; ++g)
                out[gn * HIDDEN + g * 16 + m] = __float2half(acc[g][r]);
        }
    }
}

// ---- FUSED: finesort (blocks 0..195) || mm1 (blocks 196..977) ----
// finesort and mm1 = x@W1 are data-independent (dinv scale moved to gather),
// so they share one dispatch and run concurrently: mm1's ~13us hides under
// finesort's span instead of serializing after it.
__global__ __launch_bounds__(256) void k_fsmm1(const int* __restrict__ binned,
                                               const int* __restrict__ tileCur,
                                               int* __restrict__ csr,
                                               int2* __restrict__ rse,
                                               float* __restrict__ dinv,
                                               const float* __restrict__ x,
                                               const float* __restrict__ W1,
                                               __half* __restrict__ bufA) {
    __shared__ __align__(16) char smem[35840];  // max(finesort 35840, mm128 34816)
    int bx = blockIdx.x;
    if (bx < NBLK_NODE)
        finesort_body(bx, binned, tileCur, csr, rse, dinv, smem);
    else
        mm_body<N_FEAT, float>(bx - NBLK_NODE, x, W1, bufA, smem);
}

// standalone layer-2 GEMM
__global__ __launch_bounds__(256) void k_mm2(const __half* __restrict__ a,
                                             const float* __restrict__ w,
                                             __half* __restrict__ out) {
    __shared__ __align__(16) char smem[2 * 64 * (HIDDEN + 8) * 2];  // 18432 B
    mm_body<HIDDEN, __half>(blockIdx.x, a, w, out, smem);
}

// add one fp16 row-octet (int4 = 8 halves) scaled by s into fp32 accumulators
__device__ __forceinline__ void acc_row8s(float* a, int4 rv, float s) {
    float2 f;
    f = __half22float2(*(__half2*)&rv.x); a[0] = fmaf(f.x, s, a[0]); a[1] = fmaf(f.y, s, a[1]);
    f = __half22float2(*(__half2*)&rv.y); a[2] = fmaf(f.x, s, a[2]); a[3] = fmaf(f.y, s, a[3]);
    f = __half22float2(*(__half2*)&rv.z); a[4] = fmaf(f.x, s, a[4]); a[5] = fmaf(f.y, s, a[5]);
    f = __half22float2(*(__half2*)&rv.w); a[6] = fmaf(f.x, s, a[6]); a[7] = fmaf(f.y, s, a[7]);
}

// ---- aggregation with per-edge dinv[src] scaling (round-0 loop shape) ----
// out[d,:] = relu( dinv[d] * (sum_e dinv[src]*h[src] + dinv[d]*h[d]) + b )
// One wave per node. lane = {edge slot e8 = lane>>3, feature octet q = lane&7}.
// dinv is 200KB -> L2-resident; the extra 4B load rides under the 128B row load.
__global__ void k_gather(const __half* __restrict__ h, const int* __restrict__ csr,
                         const int2* __restrict__ rse, const float* __restrict__ dinv,
                         const float* __restrict__ bias, __half* __restrict__ out) {
    int t = blockIdx.x * 256 + threadIdx.x;
    int node = __builtin_amdgcn_readfirstlane(t >> 6);  // wave-uniform
    int lane = t & 63;
    int e8 = lane >> 3;   // edge slot 0..7
    int q = lane & 7;     // features q*8 .. q*8+7
    int2 se = rse[node];
    int r0 = se.x, r1 = se.x + se.y;
    float dd = dinv[node];

    float a[8] = {0.f, 0.f, 0.f, 0.f, 0.f, 0.f, 0.f, 0.f};
    if (e8 == 0)  // self-loop row counted once, scaled by dinv[node]
        acc_row8s(a, *(const int4*)&h[(long)node * HIDDEN + q * 8], dd);

    int j = r0;
    while (j + 16 <= r1) {  // 16 edges: 2 independent 8-row batches in flight
        int sA = csr[j + e8];
        int sB = csr[j + 8 + e8];
        float dA = dinv[sA];
        float dB = dinv[sB];
        int4 rA = *(const int4*)&h[(long)sA * HIDDEN + q * 8];
        int4 rB = *(const int4*)&h[(long)sB * HIDDEN + q * 8];
        acc_row8s(a, rA, dA);
        acc_row8s(a, rB, dB);
        j += 16;
    }
    if (j + 8 <= r1) {
        int sA = csr[j + e8];
        float dA = dinv[sA];
        acc_row8s(a, *(const int4*)&h[(long)sA * HIDDEN + q * 8], dA);
        j += 8;
    }
    int rem = r1 - j;  // 0..7
    if (e8 < rem) {
        int sA = csr[j + e8];
        float dA = dinv[sA];
        acc_row8s(a, *(const int4*)&h[(long)sA * HIDDEN + q * 8], dA);
    }
    // reduce across the 8 edge slots
#pragma unroll
    for (int off = 8; off < 64; off <<= 1)
#pragma unroll
        for (int i = 0; i < 8; ++i) a[i] += __shfl_xor(a[i], off, 64);

    if (e8 == 0) {
        float4 b0 = *(const float4*)&bias[q * 8];
        float4 b1 = *(const float4*)&bias[q * 8 + 4];
        float r[8];
        r[0] = fmaxf(fmaf(a[0], dd, b0.x), 0.f);
        r[1] = fmaxf(fmaf(a[1], dd, b0.y), 0.f);
        r[2] = fmaxf(fmaf(a[2], dd, b0.z), 0.f);
        r[3] = fmaxf(fmaf(a[3], dd, b0.w), 0.f);
        r[4] = fmaxf(fmaf(a[4], dd, b1.x), 0.f);
        r[5] = fmaxf(fmaf(a[5], dd, b1.y), 0.f);
        r[6] = fmaxf(fmaf(a[6], dd, b1.z), 0.f);
        r[7] = fmaxf(fmaf(a[7], dd, b1.w), 0.f);
        __half2 h0 = __floats2half2_rn(r[0], r[1]);
        __half2 h1 = __floats2half2_rn(r[2], r[3]);
        __half2 h2 = __floats2half2_rn(r[4], r[5]);
        __half2 h3 = __floats2half2_rn(r[6], r[7]);
        int4 o;
        o.x = *(int*)&h0; o.y = *(int*)&h1; o.z = *(int*)&h2; o.w = *(int*)&h3;
        *(int4*)&out[(long)node * HIDDEN + q * 8] = o;
    }
}

// ---- logits = h @ Wout + bout, softmax over 16 classes (fp32 math) ----
__global__ void k_out(const __half* __restrict__ h, const float* __restrict__ w,
                      const float* __restrict__ b, float* __restrict__ out) {
    __shared__ float Ws[HIDDEN * N_CLASSES];
    __shared__ float bs[N_CLASSES];
    int tid = threadIdx.x;
    for (int i = tid; i < HIDDEN * N_CLASSES; i += 256) Ws[i] = w[i];
    if (tid < N_CLASSES) bs[tid] = b[tid];
    __syncthreads();
    int node = blockIdx.x * 16 + (tid >> 4);
    int c = tid & 15;
    const __half* hr = h + (long)node * HIDDEN;
    float acc = bs[c];
#pragma unroll
    for (int k = 0; k < HIDDEN; ++k)
        acc = fmaf(__half2float(hr[k]), Ws[k * N_CLASSES + c], acc);
    float m = acc;
#pragma unroll
    for (int off = 8; off; off >>= 1) m = fmaxf(m, __shfl_xor(m, off, 16));
    float ex = expf(acc - m);
    float s = ex;
#pragma unroll
    for (int off = 8; off; off >>= 1) s += __shfl_xor(s, off, 16);
    out[(long)node * N_CLASSES + c] = ex / s;
}

extern "C" void kernel_launch(void* const* d_in, const int* in_sizes, int n_in,
                              void* d_out, int out_size, void* d_ws, size_t ws_size,
                              hipStream_t stream) {
    const float* x    = (const float*)d_in[0];
    const int*   ei   = (const int*)d_in[1];
    const float* W1   = (const float*)d_in[2];
    const float* b1   = (const float*)d_in[3];
    const float* W2   = (const float*)d_in[4];
    const float* b2   = (const float*)d_in[5];
    const float* Wout = (const float*)d_in[6];
    const float* bout = (const float*)d_in[7];
    float* out = (float*)d_out;

    char* ws = (char*)d_ws;
    int2*   rse     = (int2*)ws;                       ws += 400128;   // 50000 int2
    float*  dinv    = (float*)ws;                      ws += 200192;   // 50000 f32
    int*    tileCur = (int*)ws;                        ws += 1024;
    int*    csr     = (int*)ws;                        ws += (size_t)NBLK_NODE * TCAP * 4;  // 6.42 MB
    int*    binned  = (int*)ws;                        ws += (size_t)NBLK_NODE * TCAP * 4;  // 6.42 MB
    // NOTE: binned may NOT alias bufA anymore — finesort reads binned while
    // mm1 writes bufA in the same fused dispatch.
    __half* bufA    = (__half*)ws;                     ws += 6553600;
    __half* bufB    = (__half*)ws;

    const int NB_MM = (N_NODES + 63) / 64;        // 782
    const int NB_E16 = (N_EDGES + 4095) / 4096;   // 196

    // ---- CSR build ----
    k_init<<<1, 256, 0, stream>>>(tileCur);
    k_part<<<NB_E16, 256, 0, stream>>>(ei, tileCur, binned);

    // ---- finesort || layer-1 GEMM (independent; one fused dispatch) ----
    k_fsmm1<<<NBLK_NODE + NB_MM, 256, 0, stream>>>(binned, tileCur, csr, rse, dinv,
                                                   x, W1, bufA);

    // ---- layer 1 aggregation (scales by dinv[src] inline) ----
    k_gather<<<N_NODES / 4, 256, 0, stream>>>(bufA, csr, rse, dinv, b1, bufB);

    // ---- layer 2 ----
    k_mm2<<<NB_MM, 256, 0, stream>>>(bufB, W2, bufA);
    k_gather<<<N_NODES / 4, 256, 0, stream>>>(bufA, csr, rse, dinv, b2, bufB);

    // ---- output layer + softmax ----
    k_out<<<N_NODES / 16, 256, 0, stream>>>(bufB, Wout, bout, out);
}

// Round 5
// 164.694 us; speedup vs baseline: 1.2506x; 1.0002x over previous
//
#include <hip/hip_runtime.h>
#include <hip/hip_fp16.h>

#define N_NODES 50000
#define N_EDGES 800000
#define N_FEAT 128
#define HIDDEN 64
#define N_CLASSES 16
#define NBLK_NODE 196   // number of 256-node dst tiles (ceil(50000/256))
#define TCAP 8192       // per-tile bucket capacity (recs); mean 4083, sigma ~64

typedef _Float16 f16x8 __attribute__((ext_vector_type(8)));
typedef float f32x4 __attribute__((ext_vector_type(4)));

// tileCur[t] = t*TCAP (bucket base cursors)
__global__ void k_init(int* __restrict__ tileCur) {
    int tid = threadIdx.x;
    if (tid < NBLK_NODE) tileCur[tid] = tid * TCAP;
}

// Partition edges into 196 fixed-capacity dst-tile buckets. Per block: LDS
// histogram, ONE global atomic per (block,tile) reserves a contiguous sub-run
// -> block-owned 4B record stores merge in L2. record: src | dstLocal<<16
__global__ __launch_bounds__(256) void k_part(const int* __restrict__ ei,
                                              int* __restrict__ tileCur,
                                              int* __restrict__ binned) {
    __shared__ int cnt[NBLK_NODE], base[NBLK_NODE], cur[NBLK_NODE];
    int tid = threadIdx.x;
    int start = blockIdx.x * 4096;
    if (tid < NBLK_NODE) cnt[tid] = 0;
    __syncthreads();
    int s[16], d[16];
#pragma unroll
    for (int u = 0; u < 4; ++u) {
        int e0 = start + u * 1024 + tid * 4;
        if (e0 + 4 <= N_EDGES) {
            int4 s4 = *(const int4*)&ei[e0];
            int4 d4 = *(const int4*)&ei[N_EDGES + e0];
            s[u * 4 + 0] = s4.x; s[u * 4 + 1] = s4.y; s[u * 4 + 2] = s4.z; s[u * 4 + 3] = s4.w;
            d[u * 4 + 0] = d4.x; d[u * 4 + 1] = d4.y; d[u * 4 + 2] = d4.z; d[u * 4 + 3] = d4.w;
#pragma unroll
            for (int q = 0; q < 4; ++q) atomicAdd(&cnt[d[u * 4 + q] >> 8], 1);
        } else {
#pragma unroll
            for (int q = 0; q < 4; ++q) {
                int e = e0 + q;
                if (e < N_EDGES) {
                    s[u * 4 + q] = ei[e];
                    d[u * 4 + q] = ei[N_EDGES + e];
                    atomicAdd(&cnt[d[u * 4 + q] >> 8], 1);
                } else s[u * 4 + q] = -1;
            }
        }
    }
    __syncthreads();
    if (tid < NBLK_NODE) {
        base[tid] = atomicAdd(&tileCur[tid], cnt[tid]);
        cur[tid] = 0;
    }
    __syncthreads();
#pragma unroll
    for (int u = 0; u < 16; ++u) {
        if (s[u] < 0) continue;
        int t = d[u] >> 8;
        int r = atomicAdd(&cur[t], 1);
        int p = base[t] + r;
        if (p < (t + 1) * TCAP)  // bucket-bound guard (never hit for uniform input)
            binned[p] = s[u] | ((d[u] & 255) << 16);
    }
}

// ---- finesort body (round-0 verbatim): per-tile counting sort in LDS ----
// smem layout: stage[TCAP] | sc[256] | cnt256[256] | nodeOff[256]  = 35840 B
__device__ __forceinline__ void finesort_body(int tb, const int* __restrict__ binned,
                                              const int* __restrict__ tileCur,
                                              int* __restrict__ csr,
                                              int2* __restrict__ rse,
                                              float* __restrict__ dinv, char* smem) {
    int* stage   = (int*)smem;
    int* sc      = stage + TCAP;
    int* cnt256  = sc + 256;
    int* nodeOff = cnt256 + 256;
    int tid = threadIdx.x;
    int beg = tb * TCAP;
    int m = tileCur[tb] - beg;
    if (m > TCAP) m = TCAP;
    cnt256[tid] = 0;
    __syncthreads();
    const int4* b4 = (const int4*)(binned + beg);
    int nv = m >> 2;
    for (int i = tid; i < nv; i += 256) {
        int4 r = b4[i];
        atomicAdd(&cnt256[(r.x >> 16) & 255], 1);
        atomicAdd(&cnt256[(r.y >> 16) & 255], 1);
        atomicAdd(&cnt256[(r.z >> 16) & 255], 1);
        atomicAdd(&cnt256[(r.w >> 16) & 255], 1);
    }
    for (int i = (m & ~3) + tid; i < m; i += 256)
        atomicAdd(&cnt256[(binned[beg + i] >> 16) & 255], 1);
    __syncthreads();
    int myc = cnt256[tid];
    sc[tid] = myc;
    __syncthreads();
#pragma unroll
    for (int off = 1; off < 256; off <<= 1) {
        int t = (tid >= off) ? sc[tid - off] : 0;
        __syncthreads();
        sc[tid] += t;
        __syncthreads();
    }
    int off0 = sc[tid] - myc;
    nodeOff[tid] = off0;
    int gnode = tb * 256 + tid;
    if (gnode < N_NODES) {
        dinv[gnode] = rsqrtf((float)myc + 1.0f);  // deg = in-edges + self-loop
        rse[gnode] = make_int2(beg + off0, myc);
    }
    cnt256[tid] = 0;
    __syncthreads();
    for (int i = tid; i < nv; i += 256) {
        int4 r = b4[i];
        int rr;
        rr = atomicAdd(&cnt256[(r.x >> 16) & 255], 1); stage[nodeOff[(r.x >> 16) & 255] + rr] = r.x & 0xFFFF;
        rr = atomicAdd(&cnt256[(r.y >> 16) & 255], 1); stage[nodeOff[(r.y >> 16) & 255] + rr] = r.y & 0xFFFF;
        rr = atomicAdd(&cnt256[(r.z >> 16) & 255], 1); stage[nodeOff[(r.z >> 16) & 255] + rr] = r.z & 0xFFFF;
        rr = atomicAdd(&cnt256[(r.w >> 16) & 255], 1); stage[nodeOff[(r.w >> 16) & 255] + rr] = r.w & 0xFFFF;
    }
    for (int i = (m & ~3) + tid; i < m; i += 256) {
        int rec = binned[beg + i];
        int dl = (rec >> 16) & 255;
        int rr = atomicAdd(&cnt256[dl], 1);
        stage[nodeOff[dl] + rr] = rec & 0xFFFF;
    }
    __syncthreads();
    int4* c4 = (int4*)(csr + beg);
    for (int i = tid; i < nv; i += 256) c4[i] = ((const int4*)stage)[i];
    for (int i = (m & ~3) + tid; i < m; i += 256) csr[beg + i] = stage[i];
}

// ---- MFMA GEMM body: out[n,f] = (A @ W)[n,f] * (dscale?dscale[n]:1), fp16 out
// Block = 256 thr = 4 waves = 64 nodes. Layouts as in round 0 (verified).
// smem: A_lds[64*(K+8)] halves | Wt_lds[64*(K+8)] halves
template <int K, typename TIn>
__device__ __forceinline__ void mm_body(int bx, const TIn* __restrict__ a,
                                        const float* __restrict__ w,
                                        const float* __restrict__ dscale,
                                        __half* __restrict__ out, char* smem) {
    constexpr int LDK = K + 8;
    __half* A_lds  = (__half*)smem;
    __half* Wt_lds = A_lds + 64 * LDK;
    int tid = threadIdx.x;
    long nbase = (long)bx * 64;

    // stage W transposed: w[k*64+f] (fp32) -> Wt_lds[f][k] (fp16)
    for (int i = tid; i < K * 16; i += 256) {
        int k = (i * 4) >> 6;
        int f0 = (i * 4) & 63;
        float4 v = *(const float4*)&w[i * 4];
        Wt_lds[(f0 + 0) * LDK + k] = __float2half(v.x);
        Wt_lds[(f0 + 1) * LDK + k] = __float2half(v.y);
        Wt_lds[(f0 + 2) * LDK + k] = __float2half(v.z);
        Wt_lds[(f0 + 3) * LDK + k] = __float2half(v.w);
    }
    // stage A rows -> A_lds[n][k] fp16 (8-elem chunks)
    for (int i = tid; i < 64 * K / 8; i += 256) {
        int n = (i * 8) / K;
        int k0 = (i * 8) % K;
        long gn = nbase + n;
        if constexpr (sizeof(TIn) == 4) {
            float4 v0, v1;
            if (gn < N_NODES) {
                v0 = *(const float4*)&a[gn * K + k0];
                v1 = *(const float4*)&a[gn * K + k0 + 4];
            } else {
                v0 = make_float4(0.f, 0.f, 0.f, 0.f);
                v1 = v0;
            }
            __half2* dst = (__half2*)&A_lds[n * LDK + k0];
            dst[0] = __floats2half2_rn(v0.x, v0.y);
            dst[1] = __floats2half2_rn(v0.z, v0.w);
            dst[2] = __floats2half2_rn(v1.x, v1.y);
            dst[3] = __floats2half2_rn(v1.z, v1.w);
        } else {
            int4 v = (gn < N_NODES) ? *(const int4*)&a[gn * K + k0]
                                    : make_int4(0, 0, 0, 0);
            *(int4*)&A_lds[n * LDK + k0] = v;
        }
    }
    __syncthreads();

    int wv = tid >> 6;
    int lane = tid & 63;
    int m = lane & 15;      // A row within wave tile / D col
    int quad = lane >> 4;   // 0..3
    const __half* Arow = &A_lds[(wv * 16 + m) * LDK + quad * 8];
    f32x4 acc[4] = {};      // 4 feature col-tiles of 16
#pragma unroll
    for (int t = 0; t < K; t += 32) {
        f16x8 af = *(const f16x8*)(const void*)&Arow[t];
#pragma unroll
        for (int g = 0; g < 4; ++g) {
            f16x8 bf = *(const f16x8*)(const void*)&Wt_lds[(g * 16 + m) * LDK + t + quad * 8];
            acc[g] = __builtin_amdgcn_mfma_f32_16x16x32_f16(af, bf, acc[g], 0, 0, 0);
        }
    }

    // D: row(node) = quad*4 + r, col(feat) = g*16 + m
#pragma unroll
    for (int r = 0; r < 4; ++r) {
        int n = wv * 16 + quad * 4 + r;
        long gn = nbase + n;
        if (gn < N_NODES) {
            float di = dscale ? dscale[gn] : 1.0f;
#pragma unroll
            for (int g = 0; g < 4; ++g)
                out[gn * HIDDEN + g * 16 + m] = __float2half(acc[g][r] * di);
        }
    }
}

// ---- FUSED: finesort (blocks 0..195) || mm1 (blocks 196..977) ----
// finesort and mm1 = x@W1 are data-independent (mm1 is unscaled; dinv[src]
// scaling happens inside gather1), so they share one dispatch and run
// concurrently: mm1 hides under finesort's span.
__global__ __launch_bounds__(256) void k_fsmm1(const int* __restrict__ binned,
                                               const int* __restrict__ tileCur,
                                               int* __restrict__ csr,
                                               int2* __restrict__ rse,
                                               float* __restrict__ dinv,
                                               const float* __restrict__ x,
                                               const float* __restrict__ W1,
                                               __half* __restrict__ bufA) {
    __shared__ __align__(16) char smem[35840];  // max(finesort 35840, mm128 34816)
    int bx = blockIdx.x;
    if (bx < NBLK_NODE)
        finesort_body(bx, binned, tileCur, csr, rse, dinv, smem);
    else
        mm_body<N_FEAT, float>(bx - NBLK_NODE, x, W1, nullptr, bufA, smem);
}

// standalone layer-2 GEMM: PRE-SCALES output by dinv[n] (round-0 scheme) so
// gather2 is a pure row-sum with no per-edge dinv loads (shorter dep chain).
__global__ __launch_bounds__(256) void k_mm2(const __half* __restrict__ a,
                                             const float* __restrict__ w,
                                             const float* __restrict__ dinv,
                                             __half* __restrict__ out) {
    __shared__ __align__(16) char smem[2 * 64 * (HIDDEN + 8) * 2];  // 18432 B
    mm_body<HIDDEN, __half>(blockIdx.x, a, w, dinv, out, smem);
}

// add one fp16 row-octet (int4 = 8 halves) scaled by s into fp32 accumulators
__device__ __forceinline__ void acc_row8s(float* a, int4 rv, float s) {
    float2 f;
    f = __half22float2(*(__half2*)&rv.x); a[0] = fmaf(f.x, s, a[0]); a[1] = fmaf(f.y, s, a[1]);
    f = __half22float2(*(__half2*)&rv.y); a[2] = fmaf(f.x, s, a[2]); a[3] = fmaf(f.y, s, a[3]);
    f = __half22float2(*(__half2*)&rv.z); a[4] = fmaf(f.x, s, a[4]); a[5] = fmaf(f.y, s, a[5]);
    f = __half22float2(*(__half2*)&rv.w); a[6] = fmaf(f.x, s, a[6]); a[7] = fmaf(f.y, s, a[7]);
}
__device__ __forceinline__ void acc_row8(float* a, int4 rv) {
    float2 f;
    f = __half22float2(*(__half2*)&rv.x); a[0] += f.x; a[1] += f.y;
    f = __half22float2(*(__half2*)&rv.y); a[2] += f.x; a[3] += f.y;
    f = __half22float2(*(__half2*)&rv.z); a[4] += f.x; a[5] += f.y;
    f = __half22float2(*(__half2*)&rv.w); a[6] += f.x; a[7] += f.y;
}

// ---- aggregation, DEEP-ISSUE structure ----
// out[d,:] = relu( dinv[d]*(sum_e scale_e*h[src] + self) + b )
// SCALE=true  (layer 1): scale_e = dinv[src], self = dinv[d]*h[d]
// SCALE=false (layer 2): rows pre-scaled by mm2; pure row-sum.
// One wave per node. lane = {edge slot e8 = lane>>3, feature octet q = lane&7}.
// ALL of {self row, 4 predicated csr batches, 4 predicated row batches} are
// issued up front -> serial depth = 2 dependent round-trips (rse->csr->row)
// instead of 3-4; 5 row-lines in flight per lane vs 2. deg>32 tail loop is
// ~1e-4 of nodes (Poisson mean 16). Masked-off batches load nothing; their
// zero-filled registers make the accumulate phase branch-free (VALU is idle).
template <bool SCALE>
__global__ void k_gather(const __half* __restrict__ h, const int* __restrict__ csr,
                         const int2* __restrict__ rse, const float* __restrict__ dinv,
                         const float* __restrict__ bias, __half* __restrict__ out) {
    int t = blockIdx.x * 256 + threadIdx.x;
    int node = __builtin_amdgcn_readfirstlane(t >> 6);  // wave-uniform
    int lane = t & 63;
    int e8 = lane >> 3;   // edge slot 0..7
    int q = lane & 7;     // features q*8 .. q*8+7

    // self row: independent of rse -> issues immediately
    int4 vs = make_int4(0, 0, 0, 0);
    if (e8 == 0) vs = *(const int4*)&h[(long)node * HIDDEN + q * 8];
    float dd = dinv[node];
    int2 se = rse[node];
    int r0 = se.x, deg = se.y;

    // 4 predicated csr batches (32 edge slots) — all issued back-to-back
    bool p0 = e8 < deg, p1 = e8 + 8 < deg, p2 = e8 + 16 < deg, p3 = e8 + 24 < deg;
    int c0 = 0, c1 = 0, c2 = 0, c3 = 0;
    if (p0) c0 = csr[r0 + e8];
    if (p1) c1 = csr[r0 + 8 + e8];
    if (p2) c2 = csr[r0 + 16 + e8];
    if (p3) c3 = csr[r0 + 24 + e8];

    // 4 predicated row batches (+ dinv[src] when SCALE) — all in flight
    int4 v0 = make_int4(0,0,0,0), v1 = v0, v2 = v0, v3 = v0;
    float d0 = 0.f, d1 = 0.f, d2 = 0.f, d3 = 0.f;
    if (p0) { v0 = *(const int4*)&h[(long)c0 * HIDDEN + q * 8]; if (SCALE) d0 = dinv[c0]; }
    if (p1) { v1 = *(const int4*)&h[(long)c1 * HIDDEN + q * 8]; if (SCALE) d1 = dinv[c1]; }
    if (p2) { v2 = *(const int4*)&h[(long)c2 * HIDDEN + q * 8]; if (SCALE) d2 = dinv[c2]; }
    if (p3) { v3 = *(const int4*)&h[(long)c3 * HIDDEN + q * 8]; if (SCALE) d3 = dinv[c3]; }

    float a[8] = {0.f, 0.f, 0.f, 0.f, 0.f, 0.f, 0.f, 0.f};
    if constexpr (SCALE) {
        acc_row8s(a, vs, dd);
        acc_row8s(a, v0, d0);
        acc_row8s(a, v1, d1);
        acc_row8s(a, v2, d2);
        acc_row8s(a, v3, d3);
    } else {
        acc_row8(a, vs);
        acc_row8(a, v0);
        acc_row8(a, v1);
        acc_row8(a, v2);
        acc_row8(a, v3);
    }

    // rare tail: deg > 32 (~6 nodes expected for Poisson(16))
    for (int j = 32; j < deg; j += 8) {
        if (j + e8 < deg) {
            int s = csr[r0 + j + e8];
            int4 rv = *(const int4*)&h[(long)s * HIDDEN + q * 8];
            if constexpr (SCALE) acc_row8s(a, rv, dinv[s]);
            else                 acc_row8(a, rv);
        }
    }

    // reduce across the 8 edge slots
#pragma unroll
    for (int off = 8; off < 64; off <<= 1)
#pragma unroll
        for (int i = 0; i < 8; ++i) a[i] += __shfl_xor(a[i], off, 64);

    if (e8 == 0) {
        float4 b0 = *(const float4*)&bias[q * 8];
        float4 b1 = *(const float4*)&bias[q * 8 + 4];
        float r[8];
        r[0] = fmaxf(fmaf(a[0], dd, b0.x), 0.f);
        r[1] = fmaxf(fmaf(a[1], dd, b0.y), 0.f);
        r[2] = fmaxf(fmaf(a[2], dd, b0.z), 0.f);
        r[3] = fmaxf(fmaf(a[3], dd, b0.w), 0.f);
        r[4] = fmaxf(fmaf(a[4], dd, b1.x), 0.f);
        r[5] = fmaxf(fmaf(a[5], dd, b1.y), 0.f);
        r[6] = fmaxf(fmaf(a[6], dd, b1.z), 0.f);
        r[7] = fmaxf(fmaf(a[7], dd, b1.w), 0.f);
        __half2 h0 = __floats2half2_rn(r[0], r[1]);
        __half2 h1 = __floats2half2_rn(r[2], r[3]);
        __half2 h2 = __floats2half2_rn(r[4], r[5]);
        __half2 h3 = __floats2half2_rn(r[6], r[7]);
        int4 o;
        o.x = *(int*)&h0; o.y = *(int*)&h1; o.z = *(int*)&h2; o.w = *(int*)&h3;
        *(int4*)&out[(long)node * HIDDEN + q * 8] = o;
    }
}

// ---- logits = h @ Wout + bout, softmax over 16 classes (fp32 math) ----
__global__ void k_out(const __half* __restrict__ h, const float* __restrict__ w,
                      const float* __restrict__ b, float* __restrict__ out) {
    __shared__ float Ws[HIDDEN * N_CLASSES];
    __shared__ float bs[N_CLASSES];
    int tid = threadIdx.x;
    for (int i = tid; i < HIDDEN * N_CLASSES; i += 256) Ws[i] = w[i];
    if (tid < N_CLASSES) bs[tid] = b[tid];
    __syncthreads();
    int node = blockIdx.x * 16 + (tid >> 4);
    int c = tid & 15;
    const __half* hr = h + (long)node * HIDDEN;
    float acc = bs[c];
#pragma unroll
    for (int k = 0; k < HIDDEN; ++k)
        acc = fmaf(__half2float(hr[k]), Ws[k * N_CLASSES + c], acc);
    float m = acc;
#pragma unroll
    for (int off = 8; off; off >>= 1) m = fmaxf(m, __shfl_xor(m, off, 16));
    float ex = expf(acc - m);
    float s = ex;
#pragma unroll
    for (int off = 8; off; off >>= 1) s += __shfl_xor(s, off, 16);
    out[(long)node * N_CLASSES + c] = ex / s;
}

extern "C" void kernel_launch(void* const* d_in, const int* in_sizes, int n_in,
                              void* d_out, int out_size, void* d_ws, size_t ws_size,
                              hipStream_t stream) {
    const float* x    = (const float*)d_in[0];
    const int*   ei   = (const int*)d_in[1];
    const float* W1   = (const float*)d_in[2];
    const float* b1   = (const float*)d_in[3];
    const float* W2   = (const float*)d_in[4];
    const float* b2   = (const float*)d_in[5];
    const float* Wout = (const float*)d_in[6];
    const float* bout = (const float*)d_in[7];
    float* out = (float*)d_out;

    char* ws = (char*)d_ws;
    int2*   rse     = (int2*)ws;                       ws += 400128;   // 50000 int2
    float*  dinv    = (float*)ws;                      ws += 200192;   // 50000 f32
    int*    tileCur = (int*)ws;                        ws += 1024;
    int*    csr     = (int*)ws;                        ws += (size_t)NBLK_NODE * TCAP * 4;  // 6.42 MB
    int*    binned  = (int*)ws;                        ws += (size_t)NBLK_NODE * TCAP * 4;  // 6.42 MB
    // binned may NOT alias bufA — finesort reads binned while mm1 writes bufA
    // in the same fused dispatch.
    __half* bufA    = (__half*)ws;                     ws += 6553600;
    __half* bufB    = (__half*)ws;

    const int NB_MM = (N_NODES + 63) / 64;        // 782
    const int NB_E16 = (N_EDGES + 4095) / 4096;   // 196

    // ---- CSR build ----
    k_init<<<1, 256, 0, stream>>>(tileCur);
    k_part<<<NB_E16, 256, 0, stream>>>(ei, tileCur, binned);

    // ---- finesort || layer-1 GEMM (independent; one fused dispatch) ----
    k_fsmm1<<<NBLK_NODE + NB_MM, 256, 0, stream>>>(binned, tileCur, csr, rse, dinv,
                                                   x, W1, bufA);

    // ---- layer 1 aggregation (scales by dinv[src] inline) ----
    k_gather<true><<<N_NODES / 4, 256, 0, stream>>>(bufA, csr, rse, dinv, b1, bufB);

    // ---- layer 2 (mm2 pre-scales by dinv -> gather2 is a pure row-sum) ----
    k_mm2<<<NB_MM, 256, 0, stream>>>(bufB, W2, dinv, bufA);
    k_gather<false><<<N_NODES / 4, 256, 0, stream>>>(bufA, csr, rse, dinv, b2, bufB);

    // ---- output layer + softmax ----
    k_out<<<N_NODES / 16, 256, 0, stream>>>(bufB, Wout, bout, out);
}

// Round 6
// 163.404 us; speedup vs baseline: 1.2604x; 1.0079x over previous
//
#include <hip/hip_runtime.h>
#include <hip/hip_fp16.h>

#define N_NODES 50000
#define N_EDGES 800000
#define N_FEAT 128
#define HIDDEN 64
#define N_CLASSES 16
#define NBLK_NODE 196   // number of 256-node dst tiles (ceil(50000/256))
#define TCAP 8192       // per-tile bucket capacity (recs); mean 4083, sigma ~64

typedef _Float16 f16x8 __attribute__((ext_vector_type(8)));
typedef float f32x4 __attribute__((ext_vector_type(4)));

// tileCur[t] = t*TCAP (bucket base cursors)
__global__ void k_init(int* __restrict__ tileCur) {
    int tid = threadIdx.x;
    if (tid < NBLK_NODE) tileCur[tid] = tid * TCAP;
}

// Partition edges into 196 fixed-capacity dst-tile buckets. Per block: LDS
// histogram, ONE global atomic per (block,tile) reserves a contiguous sub-run
// -> block-owned 4B record stores merge in L2. record: src | dstLocal<<16
__global__ __launch_bounds__(256) void k_part(const int* __restrict__ ei,
                                              int* __restrict__ tileCur,
                                              int* __restrict__ binned) {
    __shared__ int cnt[NBLK_NODE], base[NBLK_NODE], cur[NBLK_NODE];
    int tid = threadIdx.x;
    int start = blockIdx.x * 4096;
    if (tid < NBLK_NODE) cnt[tid] = 0;
    __syncthreads();
    int s[16], d[16];
#pragma unroll
    for (int u = 0; u < 4; ++u) {
        int e0 = start + u * 1024 + tid * 4;
        if (e0 + 4 <= N_EDGES) {
            int4 s4 = *(const int4*)&ei[e0];
            int4 d4 = *(const int4*)&ei[N_EDGES + e0];
            s[u * 4 + 0] = s4.x; s[u * 4 + 1] = s4.y; s[u * 4 + 2] = s4.z; s[u * 4 + 3] = s4.w;
            d[u * 4 + 0] = d4.x; d[u * 4 + 1] = d4.y; d[u * 4 + 2] = d4.z; d[u * 4 + 3] = d4.w;
#pragma unroll
            for (int q = 0; q < 4; ++q) atomicAdd(&cnt[d[u * 4 + q] >> 8], 1);
        } else {
#pragma unroll
            for (int q = 0; q < 4; ++q) {
                int e = e0 + q;
                if (e < N_EDGES) {
                    s[u * 4 + q] = ei[e];
                    d[u * 4 + q] = ei[N_EDGES + e];
                    atomicAdd(&cnt[d[u * 4 + q] >> 8], 1);
                } else s[u * 4 + q] = -1;
            }
        }
    }
    __syncthreads();
    if (tid < NBLK_NODE) {
        base[tid] = atomicAdd(&tileCur[tid], cnt[tid]);
        cur[tid] = 0;
    }
    __syncthreads();
#pragma unroll
    for (int u = 0; u < 16; ++u) {
        if (s[u] < 0) continue;
        int t = d[u] >> 8;
        int r = atomicAdd(&cur[t], 1);
        int p = base[t] + r;
        if (p < (t + 1) * TCAP)  // bucket-bound guard (never hit for uniform input)
            binned[p] = s[u] | ((d[u] & 255) << 16);
    }
}

// ---- finesort body, SINGLE-PASS: counting atomicAdd's return value IS the
// within-node rank (segment order irrelevant — gather only sums). Records +
// ranks live in fully-unrolled register arrays (all indices compile-time).
// shfl_up wave scan (2 barriers) replaces the 16-barrier ladder. No second
// atomic pass, no binned re-read.
// smem: stage[TCAP] | cnt256[256] | nodeOff[256] | wsum[4] = 34832 B
__device__ __forceinline__ void finesort_body(int tb, const int* __restrict__ binned,
                                              const int* __restrict__ tileCur,
                                              int* __restrict__ csr,
                                              int2* __restrict__ rse,
                                              float* __restrict__ dinv, char* smem) {
    int* stage   = (int*)smem;
    int* cnt256  = stage + TCAP;
    int* nodeOff = cnt256 + 256;
    int* wsum    = nodeOff + 256;
    int tid = threadIdx.x;
    int beg = tb * TCAP;
    int m = tileCur[tb] - beg;
    if (m > TCAP) m = TCAP;
    cnt256[tid] = 0;
    __syncthreads();
    const int4* b4 = (const int4*)(binned + beg);
    int nv = m >> 2;   // <= 2048 -> <= 8 int4 per thread at 256 thr
    int4 v[8], rk[8];
#pragma unroll
    for (int u = 0; u < 8; ++u) {
        int i = tid + u * 256;
        if (i < nv) {
            int4 r = b4[i];
            v[u] = r;
            rk[u].x = atomicAdd(&cnt256[(r.x >> 16) & 255], 1);
            rk[u].y = atomicAdd(&cnt256[(r.y >> 16) & 255], 1);
            rk[u].z = atomicAdd(&cnt256[(r.z >> 16) & 255], 1);
            rk[u].w = atomicAdd(&cnt256[(r.w >> 16) & 255], 1);
        }
    }
    int trec = -1, trk = 0;  // m&3 leftover records (src >= 0, so -1 is safe)
    int ti = (m & ~3) + tid;
    if (ti < m) {
        trec = binned[beg + ti];
        trk = atomicAdd(&cnt256[(trec >> 16) & 255], 1);
    }
    __syncthreads();
    // exclusive prefix over 256 per-node counts: shfl_up scan + wave sums
    int myc = cnt256[tid];
    int sc = myc;
#pragma unroll
    for (int off = 1; off < 64; off <<= 1) {
        int t2 = __shfl_up(sc, off, 64);
        if ((tid & 63) >= off) sc += t2;
    }
    if ((tid & 63) == 63) wsum[tid >> 6] = sc;
    __syncthreads();
    int wv = tid >> 6;
    int pre = 0;
    if (wv > 0) pre += wsum[0];
    if (wv > 1) pre += wsum[1];
    if (wv > 2) pre += wsum[2];
    int off0 = sc - myc + pre;
    nodeOff[tid] = off0;
    int gnode = tb * 256 + tid;
    if (gnode < N_NODES) {
        dinv[gnode] = rsqrtf((float)myc + 1.0f);  // deg = in-edges + self-loop
        rse[gnode] = make_int2(beg + off0, myc);
    }
    __syncthreads();
    // scatter with precomputed ranks
#pragma unroll
    for (int u = 0; u < 8; ++u) {
        int i = tid + u * 256;
        if (i < nv) {
            stage[nodeOff[(v[u].x >> 16) & 255] + rk[u].x] = v[u].x & 0xFFFF;
            stage[nodeOff[(v[u].y >> 16) & 255] + rk[u].y] = v[u].y & 0xFFFF;
            stage[nodeOff[(v[u].z >> 16) & 255] + rk[u].z] = v[u].z & 0xFFFF;
            stage[nodeOff[(v[u].w >> 16) & 255] + rk[u].w] = v[u].w & 0xFFFF;
        }
    }
    if (trec >= 0)
        stage[nodeOff[(trec >> 16) & 255] + trk] = trec & 0xFFFF;
    __syncthreads();
    int4* c4 = (int4*)(csr + beg);
    for (int i = tid; i < nv; i += 256) c4[i] = ((const int4*)stage)[i];
    for (int i = (m & ~3) + tid; i < m; i += 256) csr[beg + i] = stage[i];
}

// ---- MFMA GEMM body: out[n,f] = (A @ W)[n,f] * (dscale?dscale[n]:1), fp16 out
// Block = 256 thr = 4 waves = 64 nodes. Layouts as in round 0 (verified).
// smem: A_lds[64*(K+8)] halves | Wt_lds[64*(K+8)] halves
template <int K, typename TIn>
__device__ __forceinline__ void mm_body(int bx, const TIn* __restrict__ a,
                                        const float* __restrict__ w,
                                        const float* __restrict__ dscale,
                                        __half* __restrict__ out, char* smem) {
    constexpr int LDK = K + 8;
    __half* A_lds  = (__half*)smem;
    __half* Wt_lds = A_lds + 64 * LDK;
    int tid = threadIdx.x;
    long nbase = (long)bx * 64;

    // stage W transposed: w[k*64+f] (fp32) -> Wt_lds[f][k] (fp16)
    for (int i = tid; i < K * 16; i += 256) {
        int k = (i * 4) >> 6;
        int f0 = (i * 4) & 63;
        float4 v = *(const float4*)&w[i * 4];
        Wt_lds[(f0 + 0) * LDK + k] = __float2half(v.x);
        Wt_lds[(f0 + 1) * LDK + k] = __float2half(v.y);
        Wt_lds[(f0 + 2) * LDK + k] = __float2half(v.z);
        Wt_lds[(f0 + 3) * LDK + k] = __float2half(v.w);
    }
    // stage A rows -> A_lds[n][k] fp16 (8-elem chunks)
    for (int i = tid; i < 64 * K / 8; i += 256) {
        int n = (i * 8) / K;
        int k0 = (i * 8) % K;
        long gn = nbase + n;
        if constexpr (sizeof(TIn) == 4) {
            float4 v0, v1;
            if (gn < N_NODES) {
                v0 = *(const float4*)&a[gn * K + k0];
                v1 = *(const float4*)&a[gn * K + k0 + 4];
            } else {
                v0 = make_float4(0.f, 0.f, 0.f, 0.f);
                v1 = v0;
            }
            __half2* dst = (__half2*)&A_lds[n * LDK + k0];
            dst[0] = __floats2half2_rn(v0.x, v0.y);
            dst[1] = __floats2half2_rn(v0.z, v0.w);
            dst[2] = __floats2half2_rn(v1.x, v1.y);
            dst[3] = __floats2half2_rn(v1.z, v1.w);
        } else {
            int4 v = (gn < N_NODES) ? *(const int4*)&a[gn * K + k0]
                                    : make_int4(0, 0, 0, 0);
            *(int4*)&A_lds[n * LDK + k0] = v;
        }
    }
    __syncthreads();

    int wv = tid >> 6;
    int lane = tid & 63;
    int m = lane & 15;      // A row within wave tile / D col
    int quad = lane >> 4;   // 0..3
    const __half* Arow = &A_lds[(wv * 16 + m) * LDK + quad * 8];
    f32x4 acc[4] = {};      // 4 feature col-tiles of 16
#pragma unroll
    for (int t = 0; t < K; t += 32) {
        f16x8 af = *(const f16x8*)(const void*)&Arow[t];
#pragma unroll
        for (int g = 0; g < 4; ++g) {
            f16x8 bf = *(const f16x8*)(const void*)&Wt_lds[(g * 16 + m) * LDK + t + quad * 8];
            acc[g] = __builtin_amdgcn_mfma_f32_16x16x32_f16(af, bf, acc[g], 0, 0, 0);
        }
    }

    // D: row(node) = quad*4 + r, col(feat) = g*16 + m
#pragma unroll
    for (int r = 0; r < 4; ++r) {
        int n = wv * 16 + quad * 4 + r;
        long gn = nbase + n;
        if (gn < N_NODES) {
            float di = dscale ? dscale[gn] : 1.0f;
#pragma unroll
            for (int g = 0; g < 4; ++g)
                out[gn * HIDDEN + g * 16 + m] = __float2half(acc[g][r] * di);
        }
    }
}

// ---- FUSED: finesort (blocks 0..195) || mm1 (blocks 196..977) ----
// finesort and mm1 = x@W1 are data-independent (mm1 is unscaled; dinv[src]
// scaling happens inside gather1), so they share one dispatch and run
// concurrently: mm1 hides under finesort's span.
__global__ __launch_bounds__(256) void k_fsmm1(const int* __restrict__ binned,
                                               const int* __restrict__ tileCur,
                                               int* __restrict__ csr,
                                               int2* __restrict__ rse,
                                               float* __restrict__ dinv,
                                               const float* __restrict__ x,
                                               const float* __restrict__ W1,
                                               __half* __restrict__ bufA) {
    __shared__ __align__(16) char smem[34832];  // max(finesort 34832, mm128 34816)
    int bx = blockIdx.x;
    if (bx < NBLK_NODE)
        finesort_body(bx, binned, tileCur, csr, rse, dinv, smem);
    else
        mm_body<N_FEAT, float>(bx - NBLK_NODE, x, W1, nullptr, bufA, smem);
}

// standalone layer-2 GEMM: PRE-SCALES output by dinv[n] (round-0 scheme) so
// gather2 is a pure row-sum with no per-edge dinv loads (shorter dep chain).
__global__ __launch_bounds__(256) void k_mm2(const __half* __restrict__ a,
                                             const float* __restrict__ w,
                                             const float* __restrict__ dinv,
                                             __half* __restrict__ out) {
    __shared__ __align__(16) char smem[2 * 64 * (HIDDEN + 8) * 2];  // 18432 B
    mm_body<HIDDEN, __half>(blockIdx.x, a, w, dinv, out, smem);
}

// add one fp16 row-octet (int4 = 8 halves) scaled by s into fp32 accumulators
__device__ __forceinline__ void acc_row8s(float* a, int4 rv, float s) {
    float2 f;
    f = __half22float2(*(__half2*)&rv.x); a[0] = fmaf(f.x, s, a[0]); a[1] = fmaf(f.y, s, a[1]);
    f = __half22float2(*(__half2*)&rv.y); a[2] = fmaf(f.x, s, a[2]); a[3] = fmaf(f.y, s, a[3]);
    f = __half22float2(*(__half2*)&rv.z); a[4] = fmaf(f.x, s, a[4]); a[5] = fmaf(f.y, s, a[5]);
    f = __half22float2(*(__half2*)&rv.w); a[6] = fmaf(f.x, s, a[6]); a[7] = fmaf(f.y, s, a[7]);
}
__device__ __forceinline__ void acc_row8(float* a, int4 rv) {
    float2 f;
    f = __half22float2(*(__half2*)&rv.x); a[0] += f.x; a[1] += f.y;
    f = __half22float2(*(__half2*)&rv.y); a[2] += f.x; a[3] += f.y;
    f = __half22float2(*(__half2*)&rv.z); a[4] += f.x; a[5] += f.y;
    f = __half22float2(*(__half2*)&rv.w); a[6] += f.x; a[7] += f.y;
}

// ---- aggregation, DEEP-ISSUE structure (round-5, measured-equal-best) ----
// out[d,:] = relu( dinv[d]*(sum_e scale_e*h[src] + self) + b )
// SCALE=true  (layer 1): scale_e = dinv[src], self = dinv[d]*h[d]
// SCALE=false (layer 2): rows pre-scaled by mm2; pure row-sum.
template <bool SCALE>
__global__ void k_gather(const __half* __restrict__ h, const int* __restrict__ csr,
                         const int2* __restrict__ rse, const float* __restrict__ dinv,
                         const float* __restrict__ bias, __half* __restrict__ out) {
    int t = blockIdx.x * 256 + threadIdx.x;
    int node = __builtin_amdgcn_readfirstlane(t >> 6);  // wave-uniform
    int lane = t & 63;
    int e8 = lane >> 3;   // edge slot 0..7
    int q = lane & 7;     // features q*8 .. q*8+7

    // self row: independent of rse -> issues immediately
    int4 vs = make_int4(0, 0, 0, 0);
    if (e8 == 0) vs = *(const int4*)&h[(long)node * HIDDEN + q * 8];
    float dd = dinv[node];
    int2 se = rse[node];
    int r0 = se.x, deg = se.y;

    // 4 predicated csr batches (32 edge slots) — all issued back-to-back
    bool p0 = e8 < deg, p1 = e8 + 8 < deg, p2 = e8 + 16 < deg, p3 = e8 + 24 < deg;
    int c0 = 0, c1 = 0, c2 = 0, c3 = 0;
    if (p0) c0 = csr[r0 + e8];
    if (p1) c1 = csr[r0 + 8 + e8];
    if (p2) c2 = csr[r0 + 16 + e8];
    if (p3) c3 = csr[r0 + 24 + e8];

    // 4 predicated row batches (+ dinv[src] when SCALE) — all in flight
    int4 v0 = make_int4(0,0,0,0), v1 = v0, v2 = v0, v3 = v0;
    float d0 = 0.f, d1 = 0.f, d2 = 0.f, d3 = 0.f;
    if (p0) { v0 = *(const int4*)&h[(long)c0 * HIDDEN + q * 8]; if (SCALE) d0 = dinv[c0]; }
    if (p1) { v1 = *(const int4*)&h[(long)c1 * HIDDEN + q * 8]; if (SCALE) d1 = dinv[c1]; }
    if (p2) { v2 = *(const int4*)&h[(long)c2 * HIDDEN + q * 8]; if (SCALE) d2 = dinv[c2]; }
    if (p3) { v3 = *(const int4*)&h[(long)c3 * HIDDEN + q * 8]; if (SCALE) d3 = dinv[c3]; }

    float a[8] = {0.f, 0.f, 0.f, 0.f, 0.f, 0.f, 0.f, 0.f};
    if constexpr (SCALE) {
        acc_row8s(a, vs, dd);
        acc_row8s(a, v0, d0);
        acc_row8s(a, v1, d1);
        acc_row8s(a, v2, d2);
        acc_row8s(a, v3, d3);
    } else {
        acc_row8(a, vs);
        acc_row8(a, v0);
        acc_row8(a, v1);
        acc_row8(a, v2);
        acc_row8(a, v3);
    }

    // rare tail: deg > 32 (~6 nodes expected for Poisson(16))
    for (int j = 32; j < deg; j += 8) {
        if (j + e8 < deg) {
            int s = csr[r0 + j + e8];
            int4 rv = *(const int4*)&h[(long)s * HIDDEN + q * 8];
            if constexpr (SCALE) acc_row8s(a, rv, dinv[s]);
            else                 acc_row8(a, rv);
        }
    }

    // reduce across the 8 edge slots
#pragma unroll
    for (int off = 8; off < 64; off <<= 1)
#pragma unroll
        for (int i = 0; i < 8; ++i) a[i] += __shfl_xor(a[i], off, 64);

    if (e8 == 0) {
        float4 b0 = *(const float4*)&bias[q * 8];
        float4 b1 = *(const float4*)&bias[q * 8 + 4];
        float r[8];
        r[0] = fmaxf(fmaf(a[0], dd, b0.x), 0.f);
        r[1] = fmaxf(fmaf(a[1], dd, b0.y), 0.f);
        r[2] = fmaxf(fmaf(a[2], dd, b0.z), 0.f);
        r[3] = fmaxf(fmaf(a[3], dd, b0.w), 0.f);
        r[4] = fmaxf(fmaf(a[4], dd, b1.x), 0.f);
        r[5] = fmaxf(fmaf(a[5], dd, b1.y), 0.f);
        r[6] = fmaxf(fmaf(a[6], dd, b1.z), 0.f);
        r[7] = fmaxf(fmaf(a[7], dd, b1.w), 0.f);
        __half2 h0 = __floats2half2_rn(r[0], r[1]);
        __half2 h1 = __floats2half2_rn(r[2], r[3]);
        __half2 h2 = __floats2half2_rn(r[4], r[5]);
        __half2 h3 = __floats2half2_rn(r[6], r[7]);
        int4 o;
        o.x = *(int*)&h0; o.y = *(int*)&h1; o.z = *(int*)&h2; o.w = *(int*)&h3;
        *(int4*)&out[(long)node * HIDDEN + q * 8] = o;
    }
}

// ---- logits = h @ Wout + bout, softmax over 16 classes (fp32 math) ----
__global__ void k_out(const __half* __restrict__ h, const float* __restrict__ w,
                      const float* __restrict__ b, float* __restrict__ out) {
    __shared__ float Ws[HIDDEN * N_CLASSES];
    __shared__ float bs[N_CLASSES];
    int tid = threadIdx.x;
    for (int i = tid; i < HIDDEN * N_CLASSES; i += 256) Ws[i] = w[i];
    if (tid < N_CLASSES) bs[tid] = b[tid];
    __syncthreads();
    int node = blockIdx.x * 16 + (tid >> 4);
    int c = tid & 15;
    const __half* hr = h + (long)node * HIDDEN;
    float acc = bs[c];
#pragma unroll
    for (int k = 0; k < HIDDEN; ++k)
        acc = fmaf(__half2float(hr[k]), Ws[k * N_CLASSES + c], acc);
    float m = acc;
#pragma unroll
    for (int off = 8; off; off >>= 1) m = fmaxf(m, __shfl_xor(m, off, 16));
    float ex = expf(acc - m);
    float s = ex;
#pragma unroll
    for (int off = 8; off; off >>= 1) s += __shfl_xor(s, off, 16);
    out[(long)node * N_CLASSES + c] = ex / s;
}

extern "C" void kernel_launch(void* const* d_in, const int* in_sizes, int n_in,
                              void* d_out, int out_size, void* d_ws, size_t ws_size,
                              hipStream_t stream) {
    const float* x    = (const float*)d_in[0];
    const int*   ei   = (const int*)d_in[1];
    const float* W1   = (const float*)d_in[2];
    const float* b1   = (const float*)d_in[3];
    const float* W2   = (const float*)d_in[4];
    const float* b2   = (const float*)d_in[5];
    const float* Wout = (const float*)d_in[6];
    const float* bout = (const float*)d_in[7];
    float* out = (float*)d_out;

    char* ws = (char*)d_ws;
    int2*   rse     = (int2*)ws;                       ws += 400128;   // 50000 int2
    float*  dinv    = (float*)ws;                      ws += 200192;   // 50000 f32
    int*    tileCur = (int*)ws;                        ws += 1024;
    int*    csr     = (int*)ws;                        ws += (size_t)NBLK_NODE * TCAP * 4;  // 6.42 MB
    int*    binned  = (int*)ws;                        ws += (size_t)NBLK_NODE * TCAP * 4;  // 6.42 MB
    // binned may NOT alias bufA — finesort reads binned while mm1 writes bufA
    // in the same fused dispatch.
    __half* bufA    = (__half*)ws;                     ws += 6553600;
    __half* bufB    = (__half*)ws;

    const int NB_MM = (N_NODES + 63) / 64;        // 782
    const int NB_E16 = (N_EDGES + 4095) / 4096;   // 196

    // ---- CSR build ----
    k_init<<<1, 256, 0, stream>>>(tileCur);
    k_part<<<NB_E16, 256, 0, stream>>>(ei, tileCur, binned);

    // ---- finesort || layer-1 GEMM (independent; one fused dispatch) ----
    k_fsmm1<<<NBLK_NODE + NB_MM, 256, 0, stream>>>(binned, tileCur, csr, rse, dinv,
                                                   x, W1, bufA);

    // ---- layer 1 aggregation (scales by dinv[src] inline) ----
    k_gather<true><<<N_NODES / 4, 256, 0, stream>>>(bufA, csr, rse, dinv, b1, bufB);

    // ---- layer 2 (mm2 pre-scales by dinv -> gather2 is a pure row-sum) ----
    k_mm2<<<NB_MM, 256, 0, stream>>>(bufB, W2, dinv, bufA);
    k_gather<false><<<N_NODES / 4, 256, 0, stream>>>(bufA, csr, rse, dinv, b2, bufB);

    // ---- output layer + softmax ----
    k_out<<<N_NODES / 16, 256, 0, stream>>>(bufB, Wout, bout, out);
}